// Round 1
// baseline (776.634 us; speedup 1.0000x reference)
//
#include <hip/hip_runtime.h>
#include <hip/hip_bf16.h>

#define NN 50000
#define NR 8
#define DI 64
#define NE 800000

// ---------- helpers ----------
__device__ __forceinline__ unsigned fkey(float f) {
    unsigned b = __float_as_uint(f);
    return (b & 0x80000000u) ? ~b : (b | 0x80000000u);
}
__device__ __forceinline__ float funkey(unsigned k) {
    unsigned b = (k & 0x80000000u) ? (k ^ 0x80000000u) : ~k;
    return __uint_as_float(b);
}
__device__ __forceinline__ unsigned short f2bf(float f) {
    unsigned u = __float_as_uint(f);
    unsigned r = (u + 0x7FFFu + ((u >> 16) & 1u)) >> 16;
    return (unsigned short)r;
}
__device__ __forceinline__ float bf2f(unsigned short b) {
    return __uint_as_float(((unsigned)b) << 16);
}

// ---------- K1: projection tables  out[n][r][64] = x[n] @ W[r] + bias[r] (bf16) ----------
__global__ __launch_bounds__(256) void proj_kernel(
    const float* __restrict__ x, const float* __restrict__ W,
    const float* __restrict__ bias, unsigned short* __restrict__ out)
{
    __shared__ float xT[64][260];   // [k][node], padded for bank-conflict-free b128 reads
    __shared__ float Wl[64][64];
    __shared__ float bl[64];
    const int r  = blockIdx.y;
    const int n0 = blockIdx.x * 256;
    const int t  = threadIdx.x;

    const float* Wr = W + (size_t)r * 4096;
    for (int i = t; i < 4096; i += 256) ((float*)Wl)[i] = Wr[i];
    if (t < 64) bl[t] = bias[r * 64 + t];
    for (int i = t; i < 256 * 64; i += 256) {
        int n = i >> 6, k = i & 63;
        int ng = n0 + n;
        xT[k][n] = (ng < NN) ? x[(size_t)ng * 64 + k] : 0.f;
    }
    __syncthreads();

    const int tn = t >> 3;          // 0..31 -> nodes tn*8..tn*8+7
    const int td = (t & 7) * 8;     // d columns td..td+7
    float acc[8][8];
    #pragma unroll
    for (int i = 0; i < 8; ++i)
        #pragma unroll
        for (int j = 0; j < 8; ++j) acc[i][j] = bl[td + j];

    for (int k = 0; k < 64; ++k) {
        float xv[8], wv[8];
        #pragma unroll
        for (int i = 0; i < 8; ++i) xv[i] = xT[k][tn * 8 + i];
        #pragma unroll
        for (int j = 0; j < 8; ++j) wv[j] = Wl[k][td + j];
        #pragma unroll
        for (int i = 0; i < 8; ++i)
            #pragma unroll
            for (int j = 0; j < 8; ++j) acc[i][j] += xv[i] * wv[j];
    }

    #pragma unroll
    for (int i = 0; i < 8; ++i) {
        int n = n0 + tn * 8 + i;
        if (n >= NN) break;
        union { unsigned short u[8]; uint4 v; } pk;
        #pragma unroll
        for (int j = 0; j < 8; ++j) pk.u[j] = f2bf(acc[i][j]);
        *reinterpret_cast<uint4*>(&out[((size_t)n * NR + r) * 64 + td]) = pk.v;
    }
}

// ---------- K2: per-edge logits from tables + segment-max (fused) ----------
__global__ __launch_bounds__(256) void logits_gather_kernel(
    const unsigned short* __restrict__ pS, const unsigned short* __restrict__ pQ,
    const int* __restrict__ src, const int* __restrict__ dst,
    const int* __restrict__ rt, const int* __restrict__ nid,
    const float* __restrict__ attn,
    float* __restrict__ e_buf, unsigned* __restrict__ emax)
{
    __shared__ float al[512];       // attn: 8 * 2 * 32
    const int t = threadIdx.x;
    for (int i = t; i < 512; i += 256) al[i] = attn[i];
    __syncthreads();

    const int e = blockIdx.x * 16 + (t >> 4);
    if (e >= NE) return;
    const int sub = t & 15;         // 16 lanes per edge, 4 d-values each
    const int r = rt[e], s = src[e], q = nid[e];
    const int d0 = sub * 4;

    const ushort4 us = *reinterpret_cast<const ushort4*>(pS + ((size_t)s * NR + r) * 64 + d0);
    const ushort4 uq = *reinterpret_cast<const ushort4*>(pQ + ((size_t)q * NR + r) * 64 + d0);
    float v0 = bf2f(us.x) + bf2f(uq.x);
    float v1 = bf2f(us.y) + bf2f(uq.y);
    float v2 = bf2f(us.z) + bf2f(uq.z);
    float v3 = bf2f(us.w) + bf2f(uq.w);
    v0 = v0 > 0.f ? v0 : 0.2f * v0;
    v1 = v1 > 0.f ? v1 : 0.2f * v1;
    v2 = v2 > 0.f ? v2 : 0.2f * v2;
    v3 = v3 > 0.f ? v3 : 0.2f * v3;
    const float* a = &al[r * 64 + d0];
    float p = v0 * a[0] + v1 * a[1] + v2 * a[2] + v3 * a[3];
    p += __shfl_xor(p, 1);
    p += __shfl_xor(p, 2);
    p += __shfl_xor(p, 4);
    if ((sub & 7) == 0) {
        int h = sub >> 3;
        e_buf[(size_t)e * 2 + h] = p;
        atomicMax(&emax[(size_t)dst[e] * 2 + h], fkey(p));
    }
}

// ---------- K2-fallback: direct per-edge GEMV (relation-specialized), small workspace ----------
__global__ __launch_bounds__(256) void logits_direct_kernel(
    const float* __restrict__ feat, const float* __restrict__ nq,
    const int* __restrict__ src, const int* __restrict__ dst,
    const int* __restrict__ rt, const int* __restrict__ nid,
    const float* __restrict__ fc_src, const float* __restrict__ fc_src_b,
    const float* __restrict__ fc_qual, const float* __restrict__ fc_qual_b,
    const float* __restrict__ attn,
    float* __restrict__ e_buf, unsigned* __restrict__ emax)
{
    __shared__ float Ws[64][64];
    __shared__ float Wq[64][64];
    __shared__ float bl[64];
    __shared__ float al[64];
    const int r = blockIdx.y;
    const int t = threadIdx.x;
    for (int i = t; i < 4096; i += 256) {
        ((float*)Ws)[i] = fc_src[(size_t)r * 4096 + i];
        ((float*)Wq)[i] = fc_qual[(size_t)r * 4096 + i];
    }
    if (t < 64) {
        bl[t] = fc_src_b[r * 64 + t] + fc_qual_b[r * 64 + t];
        al[t] = attn[r * 64 + t];
    }
    __syncthreads();

    const int lane = t & 63;
    const int wid = blockIdx.x * 4 + (t >> 6);
    const int nw = gridDim.x * 4;
    for (int e = wid; e < NE; e += nw) {
        if (rt[e] != r) continue;            // wave-uniform
        const int s = src[e], q = nid[e];
        float fv = feat[(size_t)s * 64 + lane];
        float qv = nq[(size_t)q * 64 + lane];
        float acc = bl[lane];
        for (int k = 0; k < 64; ++k) {
            acc += __shfl(fv, k) * Ws[k][lane];
            acc += __shfl(qv, k) * Wq[k][lane];
        }
        acc = acc > 0.f ? acc : 0.2f * acc;
        float p = acc * al[lane];
        #pragma unroll
        for (int m = 1; m < 32; m <<= 1) p += __shfl_xor(p, m);
        if ((lane & 31) == 0) {
            int h = lane >> 5;
            e_buf[(size_t)e * 2 + h] = p;
            atomicMax(&emax[(size_t)dst[e] * 2 + h], fkey(p));
        }
    }
}

// ---------- K3: ex = exp(e - emax[dst]) in-place + denom atomics ----------
__global__ __launch_bounds__(256) void expdenom_kernel(
    const int* __restrict__ dst, float* __restrict__ e_buf,
    const unsigned* __restrict__ emax, float* __restrict__ denom)
{
    const int i = blockIdx.x * 256 + threadIdx.x;
    if (i >= NE * 2) return;
    const int e = i >> 1, h = i & 1;
    const int dn = dst[e];
    const float m = funkey(emax[(size_t)dn * 2 + h]);
    const float ex = __expf(e_buf[i] - m);
    e_buf[i] = ex;
    unsafeAtomicAdd(&denom[(size_t)dn * 2 + h], ex);
}

// ---------- K4: scatter messages  rst[dst][h][:] += feat[src][:] * a[h] ----------
__global__ __launch_bounds__(256) void scatter_kernel(
    const float* __restrict__ feat, const int* __restrict__ src, const int* __restrict__ dst,
    const float* __restrict__ ex, const float* __restrict__ denom, float* __restrict__ out)
{
    const int e = blockIdx.x * 4 + (threadIdx.x >> 6);
    if (e >= NE) return;
    const int lane = threadIdx.x & 63;
    const int s = src[e], dn = dst[e];
    const float f = feat[(size_t)s * 64 + lane];
    const float a0 = ex[(size_t)e * 2]     / denom[(size_t)dn * 2];
    const float a1 = ex[(size_t)e * 2 + 1] / denom[(size_t)dn * 2 + 1];
    unsafeAtomicAdd(&out[(size_t)dn * 128 + lane],      f * a0);
    unsafeAtomicAdd(&out[(size_t)dn * 128 + 64 + lane], f * a1);
}

extern "C" void kernel_launch(void* const* d_in, const int* in_sizes, int n_in,
                              void* d_out, int out_size, void* d_ws, size_t ws_size,
                              hipStream_t stream)
{
    const float* feat      = (const float*)d_in[0];
    const int*   src       = (const int*)d_in[1];
    const int*   dst       = (const int*)d_in[2];
    const int*   rt        = (const int*)d_in[3];
    const int*   nid       = (const int*)d_in[4];
    const float* fc_src    = (const float*)d_in[5];
    const float* fc_src_b  = (const float*)d_in[6];
    const float* nq        = (const float*)d_in[7];
    const float* fc_qual   = (const float*)d_in[8];
    const float* fc_qual_b = (const float*)d_in[9];
    const float* attn      = (const float*)d_in[10];
    float* out = (float*)d_out;

    char* ws = (char*)d_ws;
    float*    e_buf = (float*)ws;                                    // NE*2 f32
    unsigned* emax  = (unsigned*)(ws + (size_t)NE * 2 * 4);          // NN*2 keys
    float*    denom = (float*)(ws + (size_t)NE * 2 * 4 + (size_t)NN * 2 * 4);
    unsigned short* pS = (unsigned short*)(ws + (size_t)NE * 2 * 4 + (size_t)NN * 2 * 4 * 2);
    unsigned short* pQ = pS + (size_t)NN * NR * 64;
    const size_t need_tables = (size_t)NE * 2 * 4 + (size_t)NN * 2 * 4 * 2
                             + (size_t)NN * NR * 64 * 2 * 2;

    hipMemsetAsync(d_out, 0, (size_t)out_size * sizeof(float), stream);
    hipMemsetAsync(emax, 0, (size_t)NN * 2 * 4 * 2, stream);         // emax keys + denom

    if (ws_size >= need_tables) {
        dim3 g((NN + 255) / 256, NR);
        proj_kernel<<<g, 256, 0, stream>>>(feat, fc_src, fc_src_b, pS);
        proj_kernel<<<g, 256, 0, stream>>>(nq, fc_qual, fc_qual_b, pQ);
        logits_gather_kernel<<<(NE + 15) / 16, 256, 0, stream>>>(
            pS, pQ, src, dst, rt, nid, attn, e_buf, emax);
    } else {
        dim3 g(256, NR);
        logits_direct_kernel<<<g, 256, 0, stream>>>(
            feat, nq, src, dst, rt, nid, fc_src, fc_src_b, fc_qual, fc_qual_b,
            attn, e_buf, emax);
    }
    expdenom_kernel<<<(NE * 2 + 255) / 256, 256, 0, stream>>>(dst, e_buf, emax, denom);
    scatter_kernel<<<(NE + 3) / 4, 256, 0, stream>>>(feat, src, dst, e_buf, denom, out);
}

// Round 2
// 586.160 us; speedup vs baseline: 1.3250x; 1.3250x over previous
//
#include <hip/hip_runtime.h>
#include <hip/hip_bf16.h>

#define NN 50000
#define NR 8
#define DI 64
#define NE 800000

// ---------- helpers ----------
__device__ __forceinline__ unsigned fkey(float f) {
    unsigned b = __float_as_uint(f);
    return (b & 0x80000000u) ? ~b : (b | 0x80000000u);
}
__device__ __forceinline__ float funkey(unsigned k) {
    unsigned b = (k & 0x80000000u) ? (k ^ 0x80000000u) : ~k;
    return __uint_as_float(b);
}
__device__ __forceinline__ unsigned short f2bf(float f) {
    unsigned u = __float_as_uint(f);
    unsigned r = (u + 0x7FFFu + ((u >> 16) & 1u)) >> 16;
    return (unsigned short)r;
}
__device__ __forceinline__ float bf2f(unsigned short b) {
    return __uint_as_float(((unsigned)b) << 16);
}

// ---------- K1: projection tables  out[n][r][64] = x[n] @ W[r] + bias[r] (bf16) ----------
__global__ __launch_bounds__(256) void proj_kernel(
    const float* __restrict__ x, const float* __restrict__ W,
    const float* __restrict__ bias, unsigned short* __restrict__ out)
{
    __shared__ float xT[64][260];
    __shared__ float Wl[64][64];
    __shared__ float bl[64];
    const int r  = blockIdx.y;
    const int n0 = blockIdx.x * 256;
    const int t  = threadIdx.x;

    const float* Wr = W + (size_t)r * 4096;
    for (int i = t; i < 4096; i += 256) ((float*)Wl)[i] = Wr[i];
    if (t < 64) bl[t] = bias[r * 64 + t];
    for (int i = t; i < 256 * 64; i += 256) {
        int n = i >> 6, k = i & 63;
        int ng = n0 + n;
        xT[k][n] = (ng < NN) ? x[(size_t)ng * 64 + k] : 0.f;
    }
    __syncthreads();

    const int tn = t >> 3;
    const int td = (t & 7) * 8;
    float acc[8][8];
    #pragma unroll
    for (int i = 0; i < 8; ++i)
        #pragma unroll
        for (int j = 0; j < 8; ++j) acc[i][j] = bl[td + j];

    for (int k = 0; k < 64; ++k) {
        float xv[8], wv[8];
        #pragma unroll
        for (int i = 0; i < 8; ++i) xv[i] = xT[k][tn * 8 + i];
        #pragma unroll
        for (int j = 0; j < 8; ++j) wv[j] = Wl[k][td + j];
        #pragma unroll
        for (int i = 0; i < 8; ++i)
            #pragma unroll
            for (int j = 0; j < 8; ++j) acc[i][j] += xv[i] * wv[j];
    }

    #pragma unroll
    for (int i = 0; i < 8; ++i) {
        int n = n0 + tn * 8 + i;
        if (n >= NN) break;
        union { unsigned short u[8]; uint4 v; } pk;
        #pragma unroll
        for (int j = 0; j < 8; ++j) pk.u[j] = f2bf(acc[i][j]);
        *reinterpret_cast<uint4*>(&out[((size_t)n * NR + r) * 64 + td]) = pk.v;
    }
}

// ---------- K2: per-edge logits from tables (no atomics) ----------
__global__ __launch_bounds__(256) void logits_gather_kernel(
    const unsigned short* __restrict__ pS, const unsigned short* __restrict__ pQ,
    const int* __restrict__ src, const int* __restrict__ rt, const int* __restrict__ nid,
    const float* __restrict__ attn, float* __restrict__ e_buf)
{
    __shared__ float al[512];
    const int t = threadIdx.x;
    for (int i = t; i < 512; i += 256) al[i] = attn[i];
    __syncthreads();

    const int e = blockIdx.x * 16 + (t >> 4);
    if (e >= NE) return;
    const int sub = t & 15;
    const int r = rt[e], s = src[e], q = nid[e];
    const int d0 = sub * 4;

    const ushort4 us = *reinterpret_cast<const ushort4*>(pS + ((size_t)s * NR + r) * 64 + d0);
    const ushort4 uq = *reinterpret_cast<const ushort4*>(pQ + ((size_t)q * NR + r) * 64 + d0);
    float v0 = bf2f(us.x) + bf2f(uq.x);
    float v1 = bf2f(us.y) + bf2f(uq.y);
    float v2 = bf2f(us.z) + bf2f(uq.z);
    float v3 = bf2f(us.w) + bf2f(uq.w);
    v0 = v0 > 0.f ? v0 : 0.2f * v0;
    v1 = v1 > 0.f ? v1 : 0.2f * v1;
    v2 = v2 > 0.f ? v2 : 0.2f * v2;
    v3 = v3 > 0.f ? v3 : 0.2f * v3;
    const float* a = &al[r * 64 + d0];
    float p = v0 * a[0] + v1 * a[1] + v2 * a[2] + v3 * a[3];
    p += __shfl_xor(p, 1);
    p += __shfl_xor(p, 2);
    p += __shfl_xor(p, 4);
    if ((sub & 7) == 0) e_buf[(size_t)e * 2 + (sub >> 3)] = p;
}

// ---------- CSR construction ----------
__global__ __launch_bounds__(256) void hist_kernel(const int* __restrict__ dst, int* __restrict__ cnt)
{
    const int e = blockIdx.x * 256 + threadIdx.x;
    if (e < NE) atomicAdd(&cnt[dst[e]], 1);
}

__global__ __launch_bounds__(256) void scan1_kernel(
    const int* __restrict__ cnt, int* __restrict__ offs, int* __restrict__ partial)
{
    __shared__ int s[256];
    const int t = threadIdx.x, i = blockIdx.x * 256 + t;
    const int v = (i < NN) ? cnt[i] : 0;
    s[t] = v;
    __syncthreads();
    #pragma unroll
    for (int off = 1; off < 256; off <<= 1) {
        const int x = (t >= off) ? s[t - off] : 0;
        __syncthreads();
        s[t] += x;
        __syncthreads();
    }
    if (i < NN) offs[i] = s[t] - v;           // exclusive, pre-add
    if (t == 255) partial[blockIdx.x] = s[255];
}

__global__ __launch_bounds__(256) void scan2_kernel(int* __restrict__ partial, const int nblk)
{
    __shared__ int s[256];
    const int t = threadIdx.x;
    const int v = (t < nblk) ? partial[t] : 0;
    s[t] = v;
    __syncthreads();
    #pragma unroll
    for (int off = 1; off < 256; off <<= 1) {
        const int x = (t >= off) ? s[t - off] : 0;
        __syncthreads();
        s[t] += x;
        __syncthreads();
    }
    if (t < nblk) partial[t] = s[t] - v;      // exclusive
}

__global__ __launch_bounds__(256) void scan3_kernel(
    int* __restrict__ offs, const int* __restrict__ partial)
{
    const int i = blockIdx.x * 256 + threadIdx.x;
    if (i < NN) offs[i] += partial[blockIdx.x];
    if (i == 0) offs[NN] = NE;
}

__global__ __launch_bounds__(256) void fill_kernel(
    const int* __restrict__ src, const int* __restrict__ dst,
    const int* __restrict__ offs, int* __restrict__ cursor,
    const float* __restrict__ e_buf,
    int* __restrict__ perm_src, float2* __restrict__ perm_e)
{
    const int e = blockIdx.x * 256 + threadIdx.x;
    if (e >= NE) return;
    const int dn = dst[e];
    const int j = offs[dn] + atomicAdd(&cursor[dn], 1);
    perm_src[j] = src[e];
    perm_e[j] = *reinterpret_cast<const float2*>(&e_buf[(size_t)e * 2]);
}

// ---------- K4: per-node softmax + weighted aggregation, one wave per node ----------
__global__ __launch_bounds__(256) void aggregate_kernel(
    const float* __restrict__ feat, const int* __restrict__ offs,
    const int* __restrict__ perm_src, const float2* __restrict__ perm_e,
    float* __restrict__ out)
{
    const int n = blockIdx.x * 4 + (threadIdx.x >> 6);
    if (n >= NN) return;
    const int lane = threadIdx.x & 63;
    const int s0 = offs[n], s1 = offs[n + 1];
    float acc0 = 0.f, acc1 = 0.f;
    if (s1 > s0) {
        float m0 = -1e30f, m1 = -1e30f;
        for (int j = s0 + lane; j < s1; j += 64) {
            const float2 ev = perm_e[j];
            m0 = fmaxf(m0, ev.x); m1 = fmaxf(m1, ev.y);
        }
        #pragma unroll
        for (int m = 32; m; m >>= 1) {
            m0 = fmaxf(m0, __shfl_xor(m0, m));
            m1 = fmaxf(m1, __shfl_xor(m1, m));
        }
        float d0 = 0.f, d1 = 0.f;
        for (int j = s0 + lane; j < s1; j += 64) {
            const float2 ev = perm_e[j];
            d0 += __expf(ev.x - m0); d1 += __expf(ev.y - m1);
        }
        #pragma unroll
        for (int m = 32; m; m >>= 1) {
            d0 += __shfl_xor(d0, m);
            d1 += __shfl_xor(d1, m);
        }
        const float r0 = 1.f / d0, r1 = 1.f / d1;
        for (int j = s0; j < s1; ++j) {
            const float2 ev = perm_e[j];            // broadcast load
            const float w0 = __expf(ev.x - m0) * r0;
            const float w1 = __expf(ev.y - m1) * r1;
            const float f = feat[(size_t)perm_src[j] * 64 + lane];
            acc0 += f * w0; acc1 += f * w1;
        }
    }
    out[(size_t)n * 128 + lane]      = acc0;
    out[(size_t)n * 128 + 64 + lane] = acc1;
}

// ---------- fallback path (small workspace): direct logits + atomic scatter ----------
__global__ __launch_bounds__(256) void logits_direct_kernel(
    const float* __restrict__ feat, const float* __restrict__ nq,
    const int* __restrict__ src, const int* __restrict__ dst,
    const int* __restrict__ rt, const int* __restrict__ nid,
    const float* __restrict__ fc_src, const float* __restrict__ fc_src_b,
    const float* __restrict__ fc_qual, const float* __restrict__ fc_qual_b,
    const float* __restrict__ attn,
    float* __restrict__ e_buf, unsigned* __restrict__ emax)
{
    __shared__ float Ws[64][64];
    __shared__ float Wq[64][64];
    __shared__ float bl[64];
    __shared__ float al[64];
    const int r = blockIdx.y;
    const int t = threadIdx.x;
    for (int i = t; i < 4096; i += 256) {
        ((float*)Ws)[i] = fc_src[(size_t)r * 4096 + i];
        ((float*)Wq)[i] = fc_qual[(size_t)r * 4096 + i];
    }
    if (t < 64) {
        bl[t] = fc_src_b[r * 64 + t] + fc_qual_b[r * 64 + t];
        al[t] = attn[r * 64 + t];
    }
    __syncthreads();

    const int lane = t & 63;
    const int wid = blockIdx.x * 4 + (t >> 6);
    const int nw = gridDim.x * 4;
    for (int e = wid; e < NE; e += nw) {
        if (rt[e] != r) continue;
        const int s = src[e], q = nid[e];
        float fv = feat[(size_t)s * 64 + lane];
        float qv = nq[(size_t)q * 64 + lane];
        float acc = bl[lane];
        for (int k = 0; k < 64; ++k) {
            acc += __shfl(fv, k) * Ws[k][lane];
            acc += __shfl(qv, k) * Wq[k][lane];
        }
        acc = acc > 0.f ? acc : 0.2f * acc;
        float p = acc * al[lane];
        #pragma unroll
        for (int m = 1; m < 32; m <<= 1) p += __shfl_xor(p, m);
        if ((lane & 31) == 0) {
            int h = lane >> 5;
            e_buf[(size_t)e * 2 + h] = p;
            atomicMax(&emax[(size_t)dst[e] * 2 + h], fkey(p));
        }
    }
}

__global__ __launch_bounds__(256) void expdenom_kernel(
    const int* __restrict__ dst, float* __restrict__ e_buf,
    const unsigned* __restrict__ emax, float* __restrict__ denom)
{
    const int i = blockIdx.x * 256 + threadIdx.x;
    if (i >= NE * 2) return;
    const int e = i >> 1, h = i & 1;
    const int dn = dst[e];
    const float m = funkey(emax[(size_t)dn * 2 + h]);
    const float ex = __expf(e_buf[i] - m);
    e_buf[i] = ex;
    unsafeAtomicAdd(&denom[(size_t)dn * 2 + h], ex);
}

__global__ __launch_bounds__(256) void scatter_kernel(
    const float* __restrict__ feat, const int* __restrict__ src, const int* __restrict__ dst,
    const float* __restrict__ ex, const float* __restrict__ denom, float* __restrict__ out)
{
    const int e = blockIdx.x * 4 + (threadIdx.x >> 6);
    if (e >= NE) return;
    const int lane = threadIdx.x & 63;
    const int s = src[e], dn = dst[e];
    const float f = feat[(size_t)s * 64 + lane];
    const float a0 = ex[(size_t)e * 2]     / denom[(size_t)dn * 2];
    const float a1 = ex[(size_t)e * 2 + 1] / denom[(size_t)dn * 2 + 1];
    unsafeAtomicAdd(&out[(size_t)dn * 128 + lane],      f * a0);
    unsafeAtomicAdd(&out[(size_t)dn * 128 + 64 + lane], f * a1);
}

extern "C" void kernel_launch(void* const* d_in, const int* in_sizes, int n_in,
                              void* d_out, int out_size, void* d_ws, size_t ws_size,
                              hipStream_t stream)
{
    const float* feat      = (const float*)d_in[0];
    const int*   src       = (const int*)d_in[1];
    const int*   dst       = (const int*)d_in[2];
    const int*   rt        = (const int*)d_in[3];
    const int*   nid       = (const int*)d_in[4];
    const float* fc_src    = (const float*)d_in[5];
    const float* fc_src_b  = (const float*)d_in[6];
    const float* nq        = (const float*)d_in[7];
    const float* fc_qual   = (const float*)d_in[8];
    const float* fc_qual_b = (const float*)d_in[9];
    const float* attn      = (const float*)d_in[10];
    float* out = (float*)d_out;

    char* ws = (char*)d_ws;
    // main layout: [e_buf 6.4MB][pS 51.2MB][pQ 51.2MB]; CSR block aliases pS
    float* e_buf = (float*)ws;
    unsigned short* pS = (unsigned short*)(ws + (size_t)NE * 2 * 4);
    unsigned short* pQ = pS + (size_t)NN * NR * 64;
    const size_t need = (size_t)NE * 2 * 4 + (size_t)NN * NR * 64 * 2 * 2;

    // CSR arrays aliased over pS (used only after logits_gather has consumed pS/pQ)
    char* csr = (char*)pS;
    int*    cnt      = (int*)csr;                                   // NN
    int*    cursor   = (int*)(csr + 200000);                        // NN
    int*    offs     = (int*)(csr + 400000);                        // NN+1 (padded to 200016)
    int*    partial  = (int*)(csr + 600016);                        // 256
    int*    perm_src = (int*)(csr + 601040);                        // NE
    float2* perm_e   = (float2*)(csr + 601040 + (size_t)NE * 4);    // NE

    if (ws_size >= need) {
        dim3 g((NN + 255) / 256, NR);
        proj_kernel<<<g, 256, 0, stream>>>(feat, fc_src, fc_src_b, pS);
        proj_kernel<<<g, 256, 0, stream>>>(nq, fc_qual, fc_qual_b, pQ);
        logits_gather_kernel<<<(NE + 15) / 16, 256, 0, stream>>>(
            pS, pQ, src, rt, nid, attn, e_buf);

        // CSR build (overwrites pS region — safe, stream-ordered after logits)
        hipMemsetAsync(cnt, 0, 400000, stream);                     // cnt + cursor
        hist_kernel<<<(NE + 255) / 256, 256, 0, stream>>>(dst, cnt);
        const int nblk = (NN + 255) / 256;
        scan1_kernel<<<nblk, 256, 0, stream>>>(cnt, offs, partial);
        scan2_kernel<<<1, 256, 0, stream>>>(partial, nblk);
        scan3_kernel<<<nblk, 256, 0, stream>>>(offs, partial);
        fill_kernel<<<(NE + 255) / 256, 256, 0, stream>>>(
            src, dst, offs, cursor, e_buf, perm_src, perm_e);
        aggregate_kernel<<<(NN + 3) / 4, 256, 0, stream>>>(
            feat, offs, perm_src, perm_e, out);
    } else {
        unsigned* emax  = (unsigned*)(ws + (size_t)NE * 2 * 4);
        float*    denom = (float*)(ws + (size_t)NE * 2 * 4 + (size_t)NN * 2 * 4);
        hipMemsetAsync(out, 0, (size_t)out_size * sizeof(float), stream);
        hipMemsetAsync(emax, 0, (size_t)NN * 2 * 4 * 2, stream);
        dim3 g(256, NR);
        logits_direct_kernel<<<g, 256, 0, stream>>>(
            feat, nq, src, dst, rt, nid, fc_src, fc_src_b, fc_qual, fc_qual_b,
            attn, e_buf, emax);
        expdenom_kernel<<<(NE * 2 + 255) / 256, 256, 0, stream>>>(dst, e_buf, emax, denom);
        scatter_kernel<<<(NE + 3) / 4, 256, 0, stream>>>(feat, src, dst, e_buf, denom, out);
    }
}

// Round 3
// 327.874 us; speedup vs baseline: 2.3687x; 1.7878x over previous
//
#include <hip/hip_runtime.h>
#include <hip/hip_bf16.h>

#define NN 50000
#define NR 8
#define DI 64
#define NE 800000
#define NN_PAD 50048   // padded node rows for tail-safe fragment loads

typedef short bf16x8 __attribute__((ext_vector_type(8)));
typedef float f32x4  __attribute__((ext_vector_type(4)));

// ---------- helpers ----------
__device__ __forceinline__ unsigned fkey(float f) {
    unsigned b = __float_as_uint(f);
    return (b & 0x80000000u) ? ~b : (b | 0x80000000u);
}
__device__ __forceinline__ float funkey(unsigned k) {
    unsigned b = (k & 0x80000000u) ? (k ^ 0x80000000u) : ~k;
    return __uint_as_float(b);
}
__device__ __forceinline__ unsigned short f2bf(float f) {
    unsigned u = __float_as_uint(f);
    unsigned r = (u + 0x7FFFu + ((u >> 16) & 1u)) >> 16;
    return (unsigned short)r;
}
__device__ __forceinline__ float bf2f(unsigned short b) {
    return __uint_as_float(((unsigned)b) << 16);
}

// ---------- P0: convert x -> bf16, transpose W -> Wt[r][o][k] bf16 ----------
__global__ __launch_bounds__(256) void prep_kernel(
    const float* __restrict__ feat, const float* __restrict__ nq,
    const float* __restrict__ WS, const float* __restrict__ WQ,
    unsigned short* __restrict__ xS, unsigned short* __restrict__ xQ,
    unsigned short* __restrict__ WtS, unsigned short* __restrict__ WtQ)
{
    const int idx = blockIdx.x * 256 + threadIdx.x;
    const int NX = NN * 64 / 4;                      // 800000 float4s per table
    if (idx < NX) {
        const float4 v = reinterpret_cast<const float4*>(feat)[idx];
        ushort4 p; p.x = f2bf(v.x); p.y = f2bf(v.y); p.z = f2bf(v.z); p.w = f2bf(v.w);
        reinterpret_cast<ushort4*>(xS)[idx] = p;
    } else if (idx < 2 * NX) {
        const float4 v = reinterpret_cast<const float4*>(nq)[idx - NX];
        ushort4 p; p.x = f2bf(v.x); p.y = f2bf(v.y); p.z = f2bf(v.z); p.w = f2bf(v.w);
        reinterpret_cast<ushort4*>(xQ)[idx - NX] = p;
    } else {
        int i = idx - 2 * NX;                        // 2*32768 transpose elems
        if (i < 32768) {
            const int r = i >> 12, rem = i & 4095, o = rem >> 6, k = rem & 63;
            WtS[i] = f2bf(WS[(size_t)r * 4096 + k * 64 + o]);
        } else if (i < 65536) {
            i -= 32768;
            const int r = i >> 12, rem = i & 4095, o = rem >> 6, k = rem & 63;
            WtQ[i] = f2bf(WQ[(size_t)r * 4096 + k * 64 + o]);
        }
    }
}

// ---------- K1: MFMA projection  out[n][r][o] = x[n] @ W[r] + bias[r] (bf16) ----------
// D[o][n] = sum_k Wt[r][o][k] * x[n][k];  one wave per 64-node chunk, no LDS.
__global__ __launch_bounds__(256) void proj_mfma_kernel(
    const unsigned short* __restrict__ xb,   // [NN_PAD][64] bf16
    const unsigned short* __restrict__ Wt,   // [8][64][64] bf16 (o-major)
    const float* __restrict__ bias,          // [8][64] f32
    unsigned short* __restrict__ out)        // [NN][8][64] bf16
{
    const int chunk = blockIdx.x * 4 + (threadIdx.x >> 6);
    if (chunk * 64 >= NN) return;
    const int n0   = chunk * 64;
    const int lane = threadIdx.x & 63;
    const int l15  = lane & 15;
    const int g    = lane >> 4;

    // x fragments: 4 node-tiles x 2 K-frags, loaded once, reused for all 8 relations
    bf16x8 xf[4][2];
    #pragma unroll
    for (int nt = 0; nt < 4; ++nt)
        #pragma unroll
        for (int kf = 0; kf < 2; ++kf) {
            const int n = n0 + nt * 16 + l15;
            xf[nt][kf] = *reinterpret_cast<const bf16x8*>(
                xb + (size_t)n * 64 + kf * 32 + g * 8);
        }

    for (int r = 0; r < NR; ++r) {
        bf16x8 wf[4][2];
        #pragma unroll
        for (int ot = 0; ot < 4; ++ot)
            #pragma unroll
            for (int kf = 0; kf < 2; ++kf) {
                const int o = ot * 16 + l15;
                wf[ot][kf] = *reinterpret_cast<const bf16x8*>(
                    Wt + ((size_t)r * 64 + o) * 64 + kf * 32 + g * 8);
            }
        f32x4 acc[4][4];    // [ot][nt]
        #pragma unroll
        for (int ot = 0; ot < 4; ++ot)
            #pragma unroll
            for (int nt = 0; nt < 4; ++nt)
                acc[ot][nt] = (f32x4){0.f, 0.f, 0.f, 0.f};
        #pragma unroll
        for (int ot = 0; ot < 4; ++ot)
            #pragma unroll
            for (int nt = 0; nt < 4; ++nt) {
                acc[ot][nt] = __builtin_amdgcn_mfma_f32_16x16x32_bf16(
                    wf[ot][0], xf[nt][0], acc[ot][nt], 0, 0, 0);
                acc[ot][nt] = __builtin_amdgcn_mfma_f32_16x16x32_bf16(
                    wf[ot][1], xf[nt][1], acc[ot][nt], 0, 0, 0);
            }
        #pragma unroll
        for (int ot = 0; ot < 4; ++ot) {
            const float4 bv = *reinterpret_cast<const float4*>(
                bias + r * 64 + ot * 16 + g * 4);
            #pragma unroll
            for (int nt = 0; nt < 4; ++nt) {
                const int n = n0 + nt * 16 + l15;
                if (n < NN) {
                    ushort4 pk;
                    pk.x = f2bf(acc[ot][nt][0] + bv.x);
                    pk.y = f2bf(acc[ot][nt][1] + bv.y);
                    pk.z = f2bf(acc[ot][nt][2] + bv.z);
                    pk.w = f2bf(acc[ot][nt][3] + bv.w);
                    *reinterpret_cast<ushort4*>(
                        out + ((size_t)n * NR + r) * 64 + ot * 16 + g * 4) = pk;
                }
            }
        }
    }
}

// ---------- old VALU projection (mid-size workspace fallback) ----------
__global__ __launch_bounds__(256) void proj_kernel(
    const float* __restrict__ x, const float* __restrict__ W,
    const float* __restrict__ bias, unsigned short* __restrict__ out)
{
    __shared__ float xT[64][260];
    __shared__ float Wl[64][64];
    __shared__ float bl[64];
    const int r  = blockIdx.y;
    const int n0 = blockIdx.x * 256;
    const int t  = threadIdx.x;

    const float* Wr = W + (size_t)r * 4096;
    for (int i = t; i < 4096; i += 256) ((float*)Wl)[i] = Wr[i];
    if (t < 64) bl[t] = bias[r * 64 + t];
    for (int i = t; i < 256 * 64; i += 256) {
        int n = i >> 6, k = i & 63;
        int ng = n0 + n;
        xT[k][n] = (ng < NN) ? x[(size_t)ng * 64 + k] : 0.f;
    }
    __syncthreads();

    const int tn = t >> 3;
    const int td = (t & 7) * 8;
    float acc[8][8];
    #pragma unroll
    for (int i = 0; i < 8; ++i)
        #pragma unroll
        for (int j = 0; j < 8; ++j) acc[i][j] = bl[td + j];

    for (int k = 0; k < 64; ++k) {
        float xv[8], wv[8];
        #pragma unroll
        for (int i = 0; i < 8; ++i) xv[i] = xT[k][tn * 8 + i];
        #pragma unroll
        for (int j = 0; j < 8; ++j) wv[j] = Wl[k][td + j];
        #pragma unroll
        for (int i = 0; i < 8; ++i)
            #pragma unroll
            for (int j = 0; j < 8; ++j) acc[i][j] += xv[i] * wv[j];
    }

    #pragma unroll
    for (int i = 0; i < 8; ++i) {
        int n = n0 + tn * 8 + i;
        if (n >= NN) break;
        union { unsigned short u[8]; uint4 v; } pk;
        #pragma unroll
        for (int j = 0; j < 8; ++j) pk.u[j] = f2bf(acc[i][j]);
        *reinterpret_cast<uint4*>(&out[((size_t)n * NR + r) * 64 + td]) = pk.v;
    }
}

// ---------- K2: per-edge logits from tables ----------
__global__ __launch_bounds__(256) void logits_gather_kernel(
    const unsigned short* __restrict__ pS, const unsigned short* __restrict__ pQ,
    const int* __restrict__ src, const int* __restrict__ rt, const int* __restrict__ nid,
    const float* __restrict__ attn, float* __restrict__ e_buf)
{
    __shared__ float al[512];
    const int t = threadIdx.x;
    for (int i = t; i < 512; i += 256) al[i] = attn[i];
    __syncthreads();

    const int e = blockIdx.x * 16 + (t >> 4);
    if (e >= NE) return;
    const int sub = t & 15;
    const int r = rt[e], s = src[e], q = nid[e];
    const int d0 = sub * 4;

    const ushort4 us = *reinterpret_cast<const ushort4*>(pS + ((size_t)s * NR + r) * 64 + d0);
    const ushort4 uq = *reinterpret_cast<const ushort4*>(pQ + ((size_t)q * NR + r) * 64 + d0);
    float v0 = bf2f(us.x) + bf2f(uq.x);
    float v1 = bf2f(us.y) + bf2f(uq.y);
    float v2 = bf2f(us.z) + bf2f(uq.z);
    float v3 = bf2f(us.w) + bf2f(uq.w);
    v0 = v0 > 0.f ? v0 : 0.2f * v0;
    v1 = v1 > 0.f ? v1 : 0.2f * v1;
    v2 = v2 > 0.f ? v2 : 0.2f * v2;
    v3 = v3 > 0.f ? v3 : 0.2f * v3;
    const float* a = &al[r * 64 + d0];
    float p = v0 * a[0] + v1 * a[1] + v2 * a[2] + v3 * a[3];
    p += __shfl_xor(p, 1);
    p += __shfl_xor(p, 2);
    p += __shfl_xor(p, 4);
    if ((sub & 7) == 0) e_buf[(size_t)e * 2 + (sub >> 3)] = p;
}

// ---------- CSR construction ----------
__global__ __launch_bounds__(256) void hist_kernel(const int* __restrict__ dst, int* __restrict__ cnt)
{
    const int e = blockIdx.x * 256 + threadIdx.x;
    if (e < NE) atomicAdd(&cnt[dst[e]], 1);
}

__global__ __launch_bounds__(256) void scan1_kernel(
    const int* __restrict__ cnt, int* __restrict__ offs, int* __restrict__ partial)
{
    __shared__ int s[256];
    const int t = threadIdx.x, i = blockIdx.x * 256 + t;
    const int v = (i < NN) ? cnt[i] : 0;
    s[t] = v;
    __syncthreads();
    #pragma unroll
    for (int off = 1; off < 256; off <<= 1) {
        const int x = (t >= off) ? s[t - off] : 0;
        __syncthreads();
        s[t] += x;
        __syncthreads();
    }
    if (i < NN) offs[i] = s[t] - v;
    if (t == 255) partial[blockIdx.x] = s[255];
}

__global__ __launch_bounds__(256) void scan2_kernel(int* __restrict__ partial, const int nblk)
{
    __shared__ int s[256];
    const int t = threadIdx.x;
    const int v = (t < nblk) ? partial[t] : 0;
    s[t] = v;
    __syncthreads();
    #pragma unroll
    for (int off = 1; off < 256; off <<= 1) {
        const int x = (t >= off) ? s[t - off] : 0;
        __syncthreads();
        s[t] += x;
        __syncthreads();
    }
    if (t < nblk) partial[t] = s[t] - v;
}

__global__ __launch_bounds__(256) void scan3_kernel(
    int* __restrict__ offs, const int* __restrict__ partial)
{
    const int i = blockIdx.x * 256 + threadIdx.x;
    if (i < NN) offs[i] += partial[blockIdx.x];
    if (i == 0) offs[NN] = NE;
}

__global__ __launch_bounds__(256) void fill_kernel(
    const int* __restrict__ src, const int* __restrict__ dst,
    const int* __restrict__ offs, int* __restrict__ cursor,
    const float* __restrict__ e_buf,
    int* __restrict__ perm_src, float2* __restrict__ perm_e)
{
    const int e = blockIdx.x * 256 + threadIdx.x;
    if (e >= NE) return;
    const int dn = dst[e];
    const int j = offs[dn] + atomicAdd(&cursor[dn], 1);
    perm_src[j] = src[e];
    perm_e[j] = *reinterpret_cast<const float2*>(&e_buf[(size_t)e * 2]);
}

// ---------- K4: per-node softmax + weighted aggregation ----------
__global__ __launch_bounds__(256) void aggregate_kernel(
    const float* __restrict__ feat, const int* __restrict__ offs,
    const int* __restrict__ perm_src, const float2* __restrict__ perm_e,
    float* __restrict__ out)
{
    const int n = blockIdx.x * 4 + (threadIdx.x >> 6);
    if (n >= NN) return;
    const int lane = threadIdx.x & 63;
    const int s0 = offs[n], s1 = offs[n + 1];
    float acc0 = 0.f, acc1 = 0.f;
    if (s1 > s0) {
        float m0 = -1e30f, m1 = -1e30f;
        for (int j = s0 + lane; j < s1; j += 64) {
            const float2 ev = perm_e[j];
            m0 = fmaxf(m0, ev.x); m1 = fmaxf(m1, ev.y);
        }
        #pragma unroll
        for (int m = 32; m; m >>= 1) {
            m0 = fmaxf(m0, __shfl_xor(m0, m));
            m1 = fmaxf(m1, __shfl_xor(m1, m));
        }
        float d0 = 0.f, d1 = 0.f;
        for (int j = s0 + lane; j < s1; j += 64) {
            const float2 ev = perm_e[j];
            d0 += __expf(ev.x - m0); d1 += __expf(ev.y - m1);
        }
        #pragma unroll
        for (int m = 32; m; m >>= 1) {
            d0 += __shfl_xor(d0, m);
            d1 += __shfl_xor(d1, m);
        }
        const float r0 = 1.f / d0, r1 = 1.f / d1;
        for (int j = s0; j < s1; ++j) {
            const float2 ev = perm_e[j];
            const float w0 = __expf(ev.x - m0) * r0;
            const float w1 = __expf(ev.y - m1) * r1;
            const float f = feat[(size_t)perm_src[j] * 64 + lane];
            acc0 += f * w0; acc1 += f * w1;
        }
    }
    out[(size_t)n * 128 + lane]      = acc0;
    out[(size_t)n * 128 + 64 + lane] = acc1;
}

// ---------- minimal-workspace fallback: direct logits + atomic scatter ----------
__global__ __launch_bounds__(256) void logits_direct_kernel(
    const float* __restrict__ feat, const float* __restrict__ nq,
    const int* __restrict__ src, const int* __restrict__ dst,
    const int* __restrict__ rt, const int* __restrict__ nid,
    const float* __restrict__ fc_src, const float* __restrict__ fc_src_b,
    const float* __restrict__ fc_qual, const float* __restrict__ fc_qual_b,
    const float* __restrict__ attn,
    float* __restrict__ e_buf, unsigned* __restrict__ emax)
{
    __shared__ float Ws[64][64];
    __shared__ float Wq[64][64];
    __shared__ float bl[64];
    __shared__ float al[64];
    const int r = blockIdx.y;
    const int t = threadIdx.x;
    for (int i = t; i < 4096; i += 256) {
        ((float*)Ws)[i] = fc_src[(size_t)r * 4096 + i];
        ((float*)Wq)[i] = fc_qual[(size_t)r * 4096 + i];
    }
    if (t < 64) {
        bl[t] = fc_src_b[r * 64 + t] + fc_qual_b[r * 64 + t];
        al[t] = attn[r * 64 + t];
    }
    __syncthreads();

    const int lane = t & 63;
    const int wid = blockIdx.x * 4 + (t >> 6);
    const int nw = gridDim.x * 4;
    for (int e = wid; e < NE; e += nw) {
        if (rt[e] != r) continue;
        const int s = src[e], q = nid[e];
        float fv = feat[(size_t)s * 64 + lane];
        float qv = nq[(size_t)q * 64 + lane];
        float acc = bl[lane];
        for (int k = 0; k < 64; ++k) {
            acc += __shfl(fv, k) * Ws[k][lane];
            acc += __shfl(qv, k) * Wq[k][lane];
        }
        acc = acc > 0.f ? acc : 0.2f * acc;
        float p = acc * al[lane];
        #pragma unroll
        for (int m = 1; m < 32; m <<= 1) p += __shfl_xor(p, m);
        if ((lane & 31) == 0) {
            int h = lane >> 5;
            e_buf[(size_t)e * 2 + h] = p;
            atomicMax(&emax[(size_t)dst[e] * 2 + h], fkey(p));
        }
    }
}

__global__ __launch_bounds__(256) void expdenom_kernel(
    const int* __restrict__ dst, float* __restrict__ e_buf,
    const unsigned* __restrict__ emax, float* __restrict__ denom)
{
    const int i = blockIdx.x * 256 + threadIdx.x;
    if (i >= NE * 2) return;
    const int e = i >> 1, h = i & 1;
    const int dn = dst[e];
    const float m = funkey(emax[(size_t)dn * 2 + h]);
    const float ex = __expf(e_buf[i] - m);
    e_buf[i] = ex;
    unsafeAtomicAdd(&denom[(size_t)dn * 2 + h], ex);
}

__global__ __launch_bounds__(256) void scatter_kernel(
    const float* __restrict__ feat, const int* __restrict__ src, const int* __restrict__ dst,
    const float* __restrict__ ex, const float* __restrict__ denom, float* __restrict__ out)
{
    const int e = blockIdx.x * 4 + (threadIdx.x >> 6);
    if (e >= NE) return;
    const int lane = threadIdx.x & 63;
    const int s = src[e], dn = dst[e];
    const float f = feat[(size_t)s * 64 + lane];
    const float a0 = ex[(size_t)e * 2]     / denom[(size_t)dn * 2];
    const float a1 = ex[(size_t)e * 2 + 1] / denom[(size_t)dn * 2 + 1];
    unsafeAtomicAdd(&out[(size_t)dn * 128 + lane],      f * a0);
    unsafeAtomicAdd(&out[(size_t)dn * 128 + 64 + lane], f * a1);
}

extern "C" void kernel_launch(void* const* d_in, const int* in_sizes, int n_in,
                              void* d_out, int out_size, void* d_ws, size_t ws_size,
                              hipStream_t stream)
{
    const float* feat      = (const float*)d_in[0];
    const int*   src       = (const int*)d_in[1];
    const int*   dst       = (const int*)d_in[2];
    const int*   rt        = (const int*)d_in[3];
    const int*   nid       = (const int*)d_in[4];
    const float* fc_src    = (const float*)d_in[5];
    const float* fc_src_b  = (const float*)d_in[6];
    const float* nq        = (const float*)d_in[7];
    const float* fc_qual   = (const float*)d_in[8];
    const float* fc_qual_b = (const float*)d_in[9];
    const float* attn      = (const float*)d_in[10];
    float* out = (float*)d_out;

    char* ws = (char*)d_ws;

    // ---- new layout ----
    // region0 (0 .. 13,000,000): [xS 6,406,144][xQ 6,406,144][WtS 65,536][WtQ 65,536]
    //   e_buf (6.4 MB) ALIASES region0 start — written only after proj consumed it.
    // pS at 13,000,000 (51.2 MB), pQ follows (51.2 MB). CSR block aliases pS.
    const size_t XBYTES = (size_t)NN_PAD * 64 * 2;               // 6,406,144
    unsigned short* xS  = (unsigned short*)ws;
    unsigned short* xQ  = (unsigned short*)(ws + XBYTES);
    unsigned short* WtS = (unsigned short*)(ws + 2 * XBYTES);
    unsigned short* WtQ = (unsigned short*)(ws + 2 * XBYTES + 65536);
    const size_t PS_OFF = 13000000;
    const size_t TBYTES = (size_t)NN * NR * 64 * 2;              // 51,200,000
    const size_t need2  = PS_OFF + 2 * TBYTES;                   // 115.4 MB
    const size_t need1  = (size_t)NE * 2 * 4 + 2 * TBYTES;       // 108.8 MB (R2 layout)

    if (ws_size >= need2) {
        float* e_buf = (float*)ws;                               // alias region0
        unsigned short* pS = (unsigned short*)(ws + PS_OFF);
        unsigned short* pQ = pS + (size_t)NN * NR * 64;
        char* csr = (char*)pS;
        int*    cnt      = (int*)csr;
        int*    cursor   = (int*)(csr + 200000);
        int*    offs     = (int*)(csr + 400000);
        int*    partial  = (int*)(csr + 600016);
        int*    perm_src = (int*)(csr + 601040);
        float2* perm_e   = (float2*)(csr + 601040 + (size_t)NE * 4);

        prep_kernel<<<(2 * (NN * 64 / 4) + 65536 + 255) / 256, 256, 0, stream>>>(
            feat, nq, fc_src, fc_qual, xS, xQ, WtS, WtQ);
        const int nchunk = (NN + 63) / 64;                       // 782
        proj_mfma_kernel<<<(nchunk + 3) / 4, 256, 0, stream>>>(xS, WtS, fc_src_b, pS);
        proj_mfma_kernel<<<(nchunk + 3) / 4, 256, 0, stream>>>(xQ, WtQ, fc_qual_b, pQ);
        logits_gather_kernel<<<(NE + 15) / 16, 256, 0, stream>>>(
            pS, pQ, src, rt, nid, attn, e_buf);

        hipMemsetAsync(cnt, 0, 400000, stream);
        hist_kernel<<<(NE + 255) / 256, 256, 0, stream>>>(dst, cnt);
        const int nblk = (NN + 255) / 256;
        scan1_kernel<<<nblk, 256, 0, stream>>>(cnt, offs, partial);
        scan2_kernel<<<1, 256, 0, stream>>>(partial, nblk);
        scan3_kernel<<<nblk, 256, 0, stream>>>(offs, partial);
        fill_kernel<<<(NE + 255) / 256, 256, 0, stream>>>(
            src, dst, offs, cursor, e_buf, perm_src, perm_e);
        aggregate_kernel<<<(NN + 3) / 4, 256, 0, stream>>>(
            feat, offs, perm_src, perm_e, out);
    } else if (ws_size >= need1) {
        // R2 path (VALU proj)
        float* e_buf = (float*)ws;
        unsigned short* pS = (unsigned short*)(ws + (size_t)NE * 2 * 4);
        unsigned short* pQ = pS + (size_t)NN * NR * 64;
        char* csr = (char*)pS;
        int*    cnt      = (int*)csr;
        int*    cursor   = (int*)(csr + 200000);
        int*    offs     = (int*)(csr + 400000);
        int*    partial  = (int*)(csr + 600016);
        int*    perm_src = (int*)(csr + 601040);
        float2* perm_e   = (float2*)(csr + 601040 + (size_t)NE * 4);

        dim3 g((NN + 255) / 256, NR);
        proj_kernel<<<g, 256, 0, stream>>>(feat, fc_src, fc_src_b, pS);
        proj_kernel<<<g, 256, 0, stream>>>(nq, fc_qual, fc_qual_b, pQ);
        logits_gather_kernel<<<(NE + 15) / 16, 256, 0, stream>>>(
            pS, pQ, src, rt, nid, attn, e_buf);

        hipMemsetAsync(cnt, 0, 400000, stream);
        hist_kernel<<<(NE + 255) / 256, 256, 0, stream>>>(dst, cnt);
        const int nblk = (NN + 255) / 256;
        scan1_kernel<<<nblk, 256, 0, stream>>>(cnt, offs, partial);
        scan2_kernel<<<1, 256, 0, stream>>>(partial, nblk);
        scan3_kernel<<<nblk, 256, 0, stream>>>(offs, partial);
        fill_kernel<<<(NE + 255) / 256, 256, 0, stream>>>(
            src, dst, offs, cursor, e_buf, perm_src, perm_e);
        aggregate_kernel<<<(NN + 3) / 4, 256, 0, stream>>>(
            feat, offs, perm_src, perm_e, out);
    } else {
        float* e_buf = (float*)ws;
        unsigned* emax  = (unsigned*)(ws + (size_t)NE * 2 * 4);
        float*    denom = (float*)(ws + (size_t)NE * 2 * 4 + (size_t)NN * 2 * 4);
        hipMemsetAsync(out, 0, (size_t)out_size * sizeof(float), stream);
        hipMemsetAsync(emax, 0, (size_t)NN * 2 * 4 * 2, stream);
        dim3 g(256, NR);
        logits_direct_kernel<<<g, 256, 0, stream>>>(
            feat, nq, src, dst, rt, nid, fc_src, fc_src_b, fc_qual, fc_qual_b,
            attn, e_buf, emax);
        expdenom_kernel<<<(NE * 2 + 255) / 256, 256, 0, stream>>>(dst, e_buf, emax, denom);
        scatter_kernel<<<(NE + 3) / 4, 256, 0, stream>>>(feat, src, dst, e_buf, denom, out);
    }
}

// Round 4
// 278.656 us; speedup vs baseline: 2.7871x; 1.1766x over previous
//
#include <hip/hip_runtime.h>
#include <hip/hip_bf16.h>

#define NN 50000
#define NR 8
#define DI 64
#define NE 800000
#define NN_PAD 50048   // padded node rows for tail-safe fragment loads

typedef short bf16x8 __attribute__((ext_vector_type(8)));
typedef float f32x4  __attribute__((ext_vector_type(4)));

// ---------- helpers ----------
__device__ __forceinline__ unsigned fkey(float f) {
    unsigned b = __float_as_uint(f);
    return (b & 0x80000000u) ? ~b : (b | 0x80000000u);
}
__device__ __forceinline__ float funkey(unsigned k) {
    unsigned b = (k & 0x80000000u) ? (k ^ 0x80000000u) : ~k;
    return __uint_as_float(b);
}
__device__ __forceinline__ unsigned short f2bf(float f) {
    unsigned u = __float_as_uint(f);
    unsigned r = (u + 0x7FFFu + ((u >> 16) & 1u)) >> 16;
    return (unsigned short)r;
}
__device__ __forceinline__ float bf2f(unsigned short b) {
    return __uint_as_float(((unsigned)b) << 16);
}

// ---------- P0: convert x -> bf16, transpose W -> Wt[r][o][k] bf16 ----------
__global__ __launch_bounds__(256) void prep_kernel(
    const float* __restrict__ feat, const float* __restrict__ nq,
    const float* __restrict__ WS, const float* __restrict__ WQ,
    unsigned short* __restrict__ xS, unsigned short* __restrict__ xQ,
    unsigned short* __restrict__ WtS, unsigned short* __restrict__ WtQ)
{
    const int idx = blockIdx.x * 256 + threadIdx.x;
    const int NX = NN * 64 / 4;                      // 800000 float4s per table
    if (idx < NX) {
        const float4 v = reinterpret_cast<const float4*>(feat)[idx];
        ushort4 p; p.x = f2bf(v.x); p.y = f2bf(v.y); p.z = f2bf(v.z); p.w = f2bf(v.w);
        reinterpret_cast<ushort4*>(xS)[idx] = p;
    } else if (idx < 2 * NX) {
        const float4 v = reinterpret_cast<const float4*>(nq)[idx - NX];
        ushort4 p; p.x = f2bf(v.x); p.y = f2bf(v.y); p.z = f2bf(v.z); p.w = f2bf(v.w);
        reinterpret_cast<ushort4*>(xQ)[idx - NX] = p;
    } else {
        int i = idx - 2 * NX;                        // 2*32768 transpose elems
        if (i < 32768) {
            const int r = i >> 12, rem = i & 4095, o = rem >> 6, k = rem & 63;
            WtS[i] = f2bf(WS[(size_t)r * 4096 + k * 64 + o]);
        } else if (i < 65536) {
            i -= 32768;
            const int r = i >> 12, rem = i & 4095, o = rem >> 6, k = rem & 63;
            WtQ[i] = f2bf(WQ[(size_t)r * 4096 + k * 64 + o]);
        }
    }
}

// ---------- K1: MFMA projection  out[n][r][o] = x[n] @ W[r] + bias[r] (bf16) ----------
__global__ __launch_bounds__(256) void proj_mfma_kernel(
    const unsigned short* __restrict__ xb,   // [NN_PAD][64] bf16
    const unsigned short* __restrict__ Wt,   // [8][64][64] bf16 (o-major)
    const float* __restrict__ bias,          // [8][64] f32
    unsigned short* __restrict__ out)        // [NN][8][64] bf16
{
    const int chunk = blockIdx.x * 4 + (threadIdx.x >> 6);
    if (chunk * 64 >= NN) return;
    const int n0   = chunk * 64;
    const int lane = threadIdx.x & 63;
    const int l15  = lane & 15;
    const int g    = lane >> 4;

    bf16x8 xf[4][2];
    #pragma unroll
    for (int nt = 0; nt < 4; ++nt)
        #pragma unroll
        for (int kf = 0; kf < 2; ++kf) {
            const int n = n0 + nt * 16 + l15;
            xf[nt][kf] = *reinterpret_cast<const bf16x8*>(
                xb + (size_t)n * 64 + kf * 32 + g * 8);
        }

    for (int r = 0; r < NR; ++r) {
        bf16x8 wf[4][2];
        #pragma unroll
        for (int ot = 0; ot < 4; ++ot)
            #pragma unroll
            for (int kf = 0; kf < 2; ++kf) {
                const int o = ot * 16 + l15;
                wf[ot][kf] = *reinterpret_cast<const bf16x8*>(
                    Wt + ((size_t)r * 64 + o) * 64 + kf * 32 + g * 8);
            }
        f32x4 acc[4][4];    // [ot][nt]
        #pragma unroll
        for (int ot = 0; ot < 4; ++ot)
            #pragma unroll
            for (int nt = 0; nt < 4; ++nt)
                acc[ot][nt] = (f32x4){0.f, 0.f, 0.f, 0.f};
        #pragma unroll
        for (int ot = 0; ot < 4; ++ot)
            #pragma unroll
            for (int nt = 0; nt < 4; ++nt) {
                acc[ot][nt] = __builtin_amdgcn_mfma_f32_16x16x32_bf16(
                    wf[ot][0], xf[nt][0], acc[ot][nt], 0, 0, 0);
                acc[ot][nt] = __builtin_amdgcn_mfma_f32_16x16x32_bf16(
                    wf[ot][1], xf[nt][1], acc[ot][nt], 0, 0, 0);
            }
        #pragma unroll
        for (int ot = 0; ot < 4; ++ot) {
            const float4 bv = *reinterpret_cast<const float4*>(
                bias + r * 64 + ot * 16 + g * 4);
            #pragma unroll
            for (int nt = 0; nt < 4; ++nt) {
                const int n = n0 + nt * 16 + l15;
                if (n < NN) {
                    ushort4 pk;
                    pk.x = f2bf(acc[ot][nt][0] + bv.x);
                    pk.y = f2bf(acc[ot][nt][1] + bv.y);
                    pk.z = f2bf(acc[ot][nt][2] + bv.z);
                    pk.w = f2bf(acc[ot][nt][3] + bv.w);
                    *reinterpret_cast<ushort4*>(
                        out + ((size_t)n * NR + r) * 64 + ot * 16 + g * 4) = pk;
                }
            }
        }
    }
}

// ---------- old VALU projection (mid-size workspace fallback) ----------
__global__ __launch_bounds__(256) void proj_kernel(
    const float* __restrict__ x, const float* __restrict__ W,
    const float* __restrict__ bias, unsigned short* __restrict__ out)
{
    __shared__ float xT[64][260];
    __shared__ float Wl[64][64];
    __shared__ float bl[64];
    const int r  = blockIdx.y;
    const int n0 = blockIdx.x * 256;
    const int t  = threadIdx.x;

    const float* Wr = W + (size_t)r * 4096;
    for (int i = t; i < 4096; i += 256) ((float*)Wl)[i] = Wr[i];
    if (t < 64) bl[t] = bias[r * 64 + t];
    for (int i = t; i < 256 * 64; i += 256) {
        int n = i >> 6, k = i & 63;
        int ng = n0 + n;
        xT[k][n] = (ng < NN) ? x[(size_t)ng * 64 + k] : 0.f;
    }
    __syncthreads();

    const int tn = t >> 3;
    const int td = (t & 7) * 8;
    float acc[8][8];
    #pragma unroll
    for (int i = 0; i < 8; ++i)
        #pragma unroll
        for (int j = 0; j < 8; ++j) acc[i][j] = bl[td + j];

    for (int k = 0; k < 64; ++k) {
        float xv[8], wv[8];
        #pragma unroll
        for (int i = 0; i < 8; ++i) xv[i] = xT[k][tn * 8 + i];
        #pragma unroll
        for (int j = 0; j < 8; ++j) wv[j] = Wl[k][td + j];
        #pragma unroll
        for (int i = 0; i < 8; ++i)
            #pragma unroll
            for (int j = 0; j < 8; ++j) acc[i][j] += xv[i] * wv[j];
    }

    #pragma unroll
    for (int i = 0; i < 8; ++i) {
        int n = n0 + tn * 8 + i;
        if (n >= NN) break;
        union { unsigned short u[8]; uint4 v; } pk;
        #pragma unroll
        for (int j = 0; j < 8; ++j) pk.u[j] = f2bf(acc[i][j]);
        *reinterpret_cast<uint4*>(&out[((size_t)n * NR + r) * 64 + td]) = pk.v;
    }
}

// ---------- K2: per-edge logits from tables ----------
__global__ __launch_bounds__(256) void logits_gather_kernel(
    const unsigned short* __restrict__ pS, const unsigned short* __restrict__ pQ,
    const int* __restrict__ src, const int* __restrict__ rt, const int* __restrict__ nid,
    const float* __restrict__ attn, float* __restrict__ e_buf)
{
    __shared__ float al[512];
    const int t = threadIdx.x;
    for (int i = t; i < 512; i += 256) al[i] = attn[i];
    __syncthreads();

    const int e = blockIdx.x * 16 + (t >> 4);
    if (e >= NE) return;
    const int sub = t & 15;
    const int r = rt[e], s = src[e], q = nid[e];
    const int d0 = sub * 4;

    const ushort4 us = *reinterpret_cast<const ushort4*>(pS + ((size_t)s * NR + r) * 64 + d0);
    const ushort4 uq = *reinterpret_cast<const ushort4*>(pQ + ((size_t)q * NR + r) * 64 + d0);
    float v0 = bf2f(us.x) + bf2f(uq.x);
    float v1 = bf2f(us.y) + bf2f(uq.y);
    float v2 = bf2f(us.z) + bf2f(uq.z);
    float v3 = bf2f(us.w) + bf2f(uq.w);
    v0 = v0 > 0.f ? v0 : 0.2f * v0;
    v1 = v1 > 0.f ? v1 : 0.2f * v1;
    v2 = v2 > 0.f ? v2 : 0.2f * v2;
    v3 = v3 > 0.f ? v3 : 0.2f * v3;
    const float* a = &al[r * 64 + d0];
    float p = v0 * a[0] + v1 * a[1] + v2 * a[2] + v3 * a[3];
    p += __shfl_xor(p, 1);
    p += __shfl_xor(p, 2);
    p += __shfl_xor(p, 4);
    if ((sub & 7) == 0) e_buf[(size_t)e * 2 + (sub >> 3)] = p;
}

// ---------- CSR construction ----------
__global__ __launch_bounds__(256) void hist_kernel(const int* __restrict__ dst, int* __restrict__ cnt)
{
    const int e = blockIdx.x * 256 + threadIdx.x;
    if (e < NE) atomicAdd(&cnt[dst[e]], 1);
}

__global__ __launch_bounds__(256) void scan1_kernel(
    const int* __restrict__ cnt, int* __restrict__ offs, int* __restrict__ partial)
{
    __shared__ int s[256];
    const int t = threadIdx.x, i = blockIdx.x * 256 + t;
    const int v = (i < NN) ? cnt[i] : 0;
    s[t] = v;
    __syncthreads();
    #pragma unroll
    for (int off = 1; off < 256; off <<= 1) {
        const int x = (t >= off) ? s[t - off] : 0;
        __syncthreads();
        s[t] += x;
        __syncthreads();
    }
    if (i < NN) offs[i] = s[t] - v;
    if (t == 255) partial[blockIdx.x] = s[255];
}

__global__ __launch_bounds__(256) void scan2_kernel(int* __restrict__ partial, const int nblk)
{
    __shared__ int s[256];
    const int t = threadIdx.x;
    const int v = (t < nblk) ? partial[t] : 0;
    s[t] = v;
    __syncthreads();
    #pragma unroll
    for (int off = 1; off < 256; off <<= 1) {
        const int x = (t >= off) ? s[t - off] : 0;
        __syncthreads();
        s[t] += x;
        __syncthreads();
    }
    if (t < nblk) partial[t] = s[t] - v;
}

__global__ __launch_bounds__(256) void scan3_kernel(
    int* __restrict__ offs, const int* __restrict__ partial)
{
    const int i = blockIdx.x * 256 + threadIdx.x;
    if (i < NN) offs[i] += partial[blockIdx.x];
    if (i == 0) offs[NN] = NE;
}

// fill: pack {src_bits, e0, e1, 0} in one 16B scatter store
__global__ __launch_bounds__(256) void fill_kernel(
    const int* __restrict__ src, const int* __restrict__ dst,
    const int* __restrict__ offs, int* __restrict__ cursor,
    const float* __restrict__ e_buf, float4* __restrict__ perm)
{
    const int e = blockIdx.x * 256 + threadIdx.x;
    if (e >= NE) return;
    const int dn = dst[e];
    const int j = offs[dn] + atomicAdd(&cursor[dn], 1);
    const float2 ev = *reinterpret_cast<const float2*>(&e_buf[(size_t)e * 2]);
    perm[j] = make_float4(__int_as_float(src[e]), ev.x, ev.y, 0.f);
}

// ---------- K4: per-node softmax + weighted aggregation (v2) ----------
// Per 64-edge chunk: lane-parallel exp -> LDS stage {src, ex0, ex1};
// serial gather loop unrolled x4 (4 feat-row loads in flight, no expf in loop).
// Identity used: sum(f*ex)/denom == sum(f*(ex/denom)).
__global__ __launch_bounds__(256) void aggregate_kernel(
    const float* __restrict__ feat, const int* __restrict__ offs,
    const float4* __restrict__ perm, float* __restrict__ out)
{
    __shared__ float4 wbuf[4][64];
    const int wv = threadIdx.x >> 6;
    const int n = blockIdx.x * 4 + wv;
    if (n >= NN) return;
    const int lane = threadIdx.x & 63;
    const int s0 = offs[n], s1 = offs[n + 1];
    float acc00 = 0.f, acc10 = 0.f, acc01 = 0.f, acc11 = 0.f;
    float d0 = 0.f, d1 = 0.f;
    if (s1 > s0) {
        float m0 = -1e30f, m1 = -1e30f;
        for (int j = s0 + lane; j < s1; j += 64) {
            const float4 p = perm[j];
            m0 = fmaxf(m0, p.y); m1 = fmaxf(m1, p.z);
        }
        #pragma unroll
        for (int m = 32; m; m >>= 1) {
            m0 = fmaxf(m0, __shfl_xor(m0, m));
            m1 = fmaxf(m1, __shfl_xor(m1, m));
        }
        for (int c = s0; c < s1; c += 64) {
            const int cnt = min(64, s1 - c);
            if (lane < cnt) {
                const float4 p = perm[c + lane];
                const float e0 = __expf(p.y - m0);
                const float e1 = __expf(p.z - m1);
                d0 += e0; d1 += e1;
                wbuf[wv][lane] = make_float4(p.x, e0, e1, 0.f);
            }
            int k = 0;
            for (; k + 4 <= cnt; k += 4) {
                const float4 a  = wbuf[wv][k];
                const float4 b  = wbuf[wv][k + 1];
                const float4 cc = wbuf[wv][k + 2];
                const float4 dd = wbuf[wv][k + 3];
                const float fa = feat[(size_t)__float_as_uint(a.x)  * 64 + lane];
                const float fb = feat[(size_t)__float_as_uint(b.x)  * 64 + lane];
                const float fc = feat[(size_t)__float_as_uint(cc.x) * 64 + lane];
                const float fd = feat[(size_t)__float_as_uint(dd.x) * 64 + lane];
                acc00 += fa * a.y;  acc10 += fa * a.z;
                acc01 += fb * b.y;  acc11 += fb * b.z;
                acc00 += fc * cc.y; acc10 += fc * cc.z;
                acc01 += fd * dd.y; acc11 += fd * dd.z;
            }
            for (; k < cnt; ++k) {
                const float4 a = wbuf[wv][k];
                const float f = feat[(size_t)__float_as_uint(a.x) * 64 + lane];
                acc00 += f * a.y; acc10 += f * a.z;
            }
        }
        #pragma unroll
        for (int m = 32; m; m >>= 1) {
            d0 += __shfl_xor(d0, m);
            d1 += __shfl_xor(d1, m);
        }
        const float r0 = 1.f / d0, r1 = 1.f / d1;
        acc00 = (acc00 + acc01) * r0;
        acc10 = (acc10 + acc11) * r1;
    }
    out[(size_t)n * 128 + lane]      = acc00;
    out[(size_t)n * 128 + 64 + lane] = acc10;
}

// ---------- minimal-workspace fallback: direct logits + atomic scatter ----------
__global__ __launch_bounds__(256) void logits_direct_kernel(
    const float* __restrict__ feat, const float* __restrict__ nq,
    const int* __restrict__ src, const int* __restrict__ dst,
    const int* __restrict__ rt, const int* __restrict__ nid,
    const float* __restrict__ fc_src, const float* __restrict__ fc_src_b,
    const float* __restrict__ fc_qual, const float* __restrict__ fc_qual_b,
    const float* __restrict__ attn,
    float* __restrict__ e_buf, unsigned* __restrict__ emax)
{
    __shared__ float Ws[64][64];
    __shared__ float Wq[64][64];
    __shared__ float bl[64];
    __shared__ float al[64];
    const int r = blockIdx.y;
    const int t = threadIdx.x;
    for (int i = t; i < 4096; i += 256) {
        ((float*)Ws)[i] = fc_src[(size_t)r * 4096 + i];
        ((float*)Wq)[i] = fc_qual[(size_t)r * 4096 + i];
    }
    if (t < 64) {
        bl[t] = fc_src_b[r * 64 + t] + fc_qual_b[r * 64 + t];
        al[t] = attn[r * 64 + t];
    }
    __syncthreads();

    const int lane = t & 63;
    const int wid = blockIdx.x * 4 + (t >> 6);
    const int nw = gridDim.x * 4;
    for (int e = wid; e < NE; e += nw) {
        if (rt[e] != r) continue;
        const int s = src[e], q = nid[e];
        float fv = feat[(size_t)s * 64 + lane];
        float qv = nq[(size_t)q * 64 + lane];
        float acc = bl[lane];
        for (int k = 0; k < 64; ++k) {
            acc += __shfl(fv, k) * Ws[k][lane];
            acc += __shfl(qv, k) * Wq[k][lane];
        }
        acc = acc > 0.f ? acc : 0.2f * acc;
        float p = acc * al[lane];
        #pragma unroll
        for (int m = 1; m < 32; m <<= 1) p += __shfl_xor(p, m);
        if ((lane & 31) == 0) {
            int h = lane >> 5;
            e_buf[(size_t)e * 2 + h] = p;
            atomicMax(&emax[(size_t)dst[e] * 2 + h], fkey(p));
        }
    }
}

__global__ __launch_bounds__(256) void expdenom_kernel(
    const int* __restrict__ dst, float* __restrict__ e_buf,
    const unsigned* __restrict__ emax, float* __restrict__ denom)
{
    const int i = blockIdx.x * 256 + threadIdx.x;
    if (i >= NE * 2) return;
    const int e = i >> 1, h = i & 1;
    const int dn = dst[e];
    const float m = funkey(emax[(size_t)dn * 2 + h]);
    const float ex = __expf(e_buf[i] - m);
    e_buf[i] = ex;
    unsafeAtomicAdd(&denom[(size_t)dn * 2 + h], ex);
}

__global__ __launch_bounds__(256) void scatter_kernel(
    const float* __restrict__ feat, const int* __restrict__ src, const int* __restrict__ dst,
    const float* __restrict__ ex, const float* __restrict__ denom, float* __restrict__ out)
{
    const int e = blockIdx.x * 4 + (threadIdx.x >> 6);
    if (e >= NE) return;
    const int lane = threadIdx.x & 63;
    const int s = src[e], dn = dst[e];
    const float f = feat[(size_t)s * 64 + lane];
    const float a0 = ex[(size_t)e * 2]     / denom[(size_t)dn * 2];
    const float a1 = ex[(size_t)e * 2 + 1] / denom[(size_t)dn * 2 + 1];
    unsafeAtomicAdd(&out[(size_t)dn * 128 + lane],      f * a0);
    unsafeAtomicAdd(&out[(size_t)dn * 128 + 64 + lane], f * a1);
}

extern "C" void kernel_launch(void* const* d_in, const int* in_sizes, int n_in,
                              void* d_out, int out_size, void* d_ws, size_t ws_size,
                              hipStream_t stream)
{
    const float* feat      = (const float*)d_in[0];
    const int*   src       = (const int*)d_in[1];
    const int*   dst       = (const int*)d_in[2];
    const int*   rt        = (const int*)d_in[3];
    const int*   nid       = (const int*)d_in[4];
    const float* fc_src    = (const float*)d_in[5];
    const float* fc_src_b  = (const float*)d_in[6];
    const float* nq        = (const float*)d_in[7];
    const float* fc_qual   = (const float*)d_in[8];
    const float* fc_qual_b = (const float*)d_in[9];
    const float* attn      = (const float*)d_in[10];
    float* out = (float*)d_out;

    char* ws = (char*)d_ws;

    const size_t XBYTES = (size_t)NN_PAD * 64 * 2;               // 6,406,144
    unsigned short* xS  = (unsigned short*)ws;
    unsigned short* xQ  = (unsigned short*)(ws + XBYTES);
    unsigned short* WtS = (unsigned short*)(ws + 2 * XBYTES);
    unsigned short* WtQ = (unsigned short*)(ws + 2 * XBYTES + 65536);
    const size_t PS_OFF = 13000000;
    const size_t TBYTES = (size_t)NN * NR * 64 * 2;              // 51,200,000
    const size_t need2  = PS_OFF + 2 * TBYTES;                   // 115.4 MB
    const size_t need1  = (size_t)NE * 2 * 4 + 2 * TBYTES;       // 108.8 MB

    if (ws_size >= need2) {
        float* e_buf = (float*)ws;                               // alias region0
        unsigned short* pS = (unsigned short*)(ws + PS_OFF);
        unsigned short* pQ = pS + (size_t)NN * NR * 64;
        char* csr = (char*)pS;
        int*    cnt      = (int*)csr;
        int*    cursor   = (int*)(csr + 200000);
        int*    offs     = (int*)(csr + 400000);
        int*    partial  = (int*)(csr + 600016);
        float4* perm     = (float4*)(csr + 601040);              // NE float4 (16B-aligned)

        prep_kernel<<<(2 * (NN * 64 / 4) + 65536 + 255) / 256, 256, 0, stream>>>(
            feat, nq, fc_src, fc_qual, xS, xQ, WtS, WtQ);
        const int nchunk = (NN + 63) / 64;                       // 782
        proj_mfma_kernel<<<(nchunk + 3) / 4, 256, 0, stream>>>(xS, WtS, fc_src_b, pS);
        proj_mfma_kernel<<<(nchunk + 3) / 4, 256, 0, stream>>>(xQ, WtQ, fc_qual_b, pQ);
        logits_gather_kernel<<<(NE + 15) / 16, 256, 0, stream>>>(
            pS, pQ, src, rt, nid, attn, e_buf);

        hipMemsetAsync(cnt, 0, 400000, stream);
        hist_kernel<<<(NE + 255) / 256, 256, 0, stream>>>(dst, cnt);
        const int nblk = (NN + 255) / 256;
        scan1_kernel<<<nblk, 256, 0, stream>>>(cnt, offs, partial);
        scan2_kernel<<<1, 256, 0, stream>>>(partial, nblk);
        scan3_kernel<<<nblk, 256, 0, stream>>>(offs, partial);
        fill_kernel<<<(NE + 255) / 256, 256, 0, stream>>>(
            src, dst, offs, cursor, e_buf, perm);
        aggregate_kernel<<<(NN + 3) / 4, 256, 0, stream>>>(
            feat, offs, perm, out);
    } else if (ws_size >= need1) {
        float* e_buf = (float*)ws;
        unsigned short* pS = (unsigned short*)(ws + (size_t)NE * 2 * 4);
        unsigned short* pQ = pS + (size_t)NN * NR * 64;
        char* csr = (char*)pS;
        int*    cnt      = (int*)csr;
        int*    cursor   = (int*)(csr + 200000);
        int*    offs     = (int*)(csr + 400000);
        int*    partial  = (int*)(csr + 600016);
        float4* perm     = (float4*)(csr + 601040);

        dim3 g((NN + 255) / 256, NR);
        proj_kernel<<<g, 256, 0, stream>>>(feat, fc_src, fc_src_b, pS);
        proj_kernel<<<g, 256, 0, stream>>>(nq, fc_qual, fc_qual_b, pQ);
        logits_gather_kernel<<<(NE + 15) / 16, 256, 0, stream>>>(
            pS, pQ, src, rt, nid, attn, e_buf);

        hipMemsetAsync(cnt, 0, 400000, stream);
        hist_kernel<<<(NE + 255) / 256, 256, 0, stream>>>(dst, cnt);
        const int nblk = (NN + 255) / 256;
        scan1_kernel<<<nblk, 256, 0, stream>>>(cnt, offs, partial);
        scan2_kernel<<<1, 256, 0, stream>>>(partial, nblk);
        scan3_kernel<<<nblk, 256, 0, stream>>>(offs, partial);
        fill_kernel<<<(NE + 255) / 256, 256, 0, stream>>>(
            src, dst, offs, cursor, e_buf, perm);
        aggregate_kernel<<<(NN + 3) / 4, 256, 0, stream>>>(
            feat, offs, perm, out);
    } else {
        float* e_buf = (float*)ws;
        unsigned* emax  = (unsigned*)(ws + (size_t)NE * 2 * 4);
        float*    denom = (float*)(ws + (size_t)NE * 2 * 4 + (size_t)NN * 2 * 4);
        hipMemsetAsync(out, 0, (size_t)out_size * sizeof(float), stream);
        hipMemsetAsync(emax, 0, (size_t)NN * 2 * 4 * 2, stream);
        dim3 g(256, NR);
        logits_direct_kernel<<<g, 256, 0, stream>>>(
            feat, nq, src, dst, rt, nid, fc_src, fc_src_b, fc_qual, fc_qual_b,
            attn, e_buf, emax);
        expdenom_kernel<<<(NE * 2 + 255) / 256, 256, 0, stream>>>(dst, e_buf, emax, denom);
        scatter_kernel<<<(NE + 3) / 4, 256, 0, stream>>>(feat, src, dst, e_buf, denom, out);
    }
}

// Round 5
// 227.426 us; speedup vs baseline: 3.4149x; 1.2253x over previous
//
#include <hip/hip_runtime.h>
#include <hip/hip_bf16.h>

#define NN 50000
#define NR 8
#define DI 64
#define NE 800000
#define NN_PAD 50048   // padded node rows for tail-safe fragment loads

typedef short bf16x8 __attribute__((ext_vector_type(8)));
typedef float f32x4  __attribute__((ext_vector_type(4)));
typedef unsigned short u16x8 __attribute__((ext_vector_type(8)));

// ---------- helpers ----------
__device__ __forceinline__ unsigned fkey(float f) {
    unsigned b = __float_as_uint(f);
    return (b & 0x80000000u) ? ~b : (b | 0x80000000u);
}
__device__ __forceinline__ float funkey(unsigned k) {
    unsigned b = (k & 0x80000000u) ? (k ^ 0x80000000u) : ~k;
    return __uint_as_float(b);
}
__device__ __forceinline__ unsigned short f2bf(float f) {
    unsigned u = __float_as_uint(f);
    unsigned r = (u + 0x7FFFu + ((u >> 16) & 1u)) >> 16;
    return (unsigned short)r;
}
__device__ __forceinline__ float bf2f(unsigned short b) {
    return __uint_as_float(((unsigned)b) << 16);
}

// ---------- P0: convert x -> bf16, transpose W -> Wt[r][o][k] bf16 ----------
__global__ __launch_bounds__(256) void prep_kernel(
    const float* __restrict__ feat, const float* __restrict__ nq,
    const float* __restrict__ WS, const float* __restrict__ WQ,
    unsigned short* __restrict__ xS, unsigned short* __restrict__ xQ,
    unsigned short* __restrict__ WtS, unsigned short* __restrict__ WtQ)
{
    const int idx = blockIdx.x * 256 + threadIdx.x;
    const int NX = NN * 64 / 4;                      // 800000 float4s per table
    if (idx < NX) {
        const float4 v = reinterpret_cast<const float4*>(feat)[idx];
        ushort4 p; p.x = f2bf(v.x); p.y = f2bf(v.y); p.z = f2bf(v.z); p.w = f2bf(v.w);
        reinterpret_cast<ushort4*>(xS)[idx] = p;
    } else if (idx < 2 * NX) {
        const float4 v = reinterpret_cast<const float4*>(nq)[idx - NX];
        ushort4 p; p.x = f2bf(v.x); p.y = f2bf(v.y); p.z = f2bf(v.z); p.w = f2bf(v.w);
        reinterpret_cast<ushort4*>(xQ)[idx - NX] = p;
    } else {
        int i = idx - 2 * NX;                        // 2*32768 transpose elems
        if (i < 32768) {
            const int r = i >> 12, rem = i & 4095, o = rem >> 6, k = rem & 63;
            WtS[i] = f2bf(WS[(size_t)r * 4096 + k * 64 + o]);
        } else if (i < 65536) {
            i -= 32768;
            const int r = i >> 12, rem = i & 4095, o = rem >> 6, k = rem & 63;
            WtQ[i] = f2bf(WQ[(size_t)r * 4096 + k * 64 + o]);
        }
    }
}

// ---------- K1: MFMA projection (both tables in one launch, blockIdx.y selects) ----------
__global__ __launch_bounds__(256) void proj_mfma_kernel(
    const unsigned short* __restrict__ xSb, const unsigned short* __restrict__ xQb,
    const unsigned short* __restrict__ WtS, const unsigned short* __restrict__ WtQ,
    const float* __restrict__ biasS, const float* __restrict__ biasQ,
    unsigned short* __restrict__ pS, unsigned short* __restrict__ pQ)
{
    const unsigned short* xb   = blockIdx.y ? xQb  : xSb;
    const unsigned short* Wt   = blockIdx.y ? WtQ  : WtS;
    const float*          bias = blockIdx.y ? biasQ : biasS;
    unsigned short*       out  = blockIdx.y ? pQ   : pS;

    const int chunk = blockIdx.x * 4 + (threadIdx.x >> 6);
    if (chunk * 64 >= NN) return;
    const int n0   = chunk * 64;
    const int lane = threadIdx.x & 63;
    const int l15  = lane & 15;
    const int g    = lane >> 4;

    bf16x8 xf[4][2];
    #pragma unroll
    for (int nt = 0; nt < 4; ++nt)
        #pragma unroll
        for (int kf = 0; kf < 2; ++kf) {
            const int n = n0 + nt * 16 + l15;
            xf[nt][kf] = *reinterpret_cast<const bf16x8*>(
                xb + (size_t)n * 64 + kf * 32 + g * 8);
        }

    for (int r = 0; r < NR; ++r) {
        bf16x8 wf[4][2];
        #pragma unroll
        for (int ot = 0; ot < 4; ++ot)
            #pragma unroll
            for (int kf = 0; kf < 2; ++kf) {
                const int o = ot * 16 + l15;
                wf[ot][kf] = *reinterpret_cast<const bf16x8*>(
                    Wt + ((size_t)r * 64 + o) * 64 + kf * 32 + g * 8);
            }
        f32x4 acc[4][4];    // [ot][nt]
        #pragma unroll
        for (int ot = 0; ot < 4; ++ot)
            #pragma unroll
            for (int nt = 0; nt < 4; ++nt)
                acc[ot][nt] = (f32x4){0.f, 0.f, 0.f, 0.f};
        #pragma unroll
        for (int ot = 0; ot < 4; ++ot)
            #pragma unroll
            for (int nt = 0; nt < 4; ++nt) {
                acc[ot][nt] = __builtin_amdgcn_mfma_f32_16x16x32_bf16(
                    wf[ot][0], xf[nt][0], acc[ot][nt], 0, 0, 0);
                acc[ot][nt] = __builtin_amdgcn_mfma_f32_16x16x32_bf16(
                    wf[ot][1], xf[nt][1], acc[ot][nt], 0, 0, 0);
            }
        #pragma unroll
        for (int ot = 0; ot < 4; ++ot) {
            const float4 bv = *reinterpret_cast<const float4*>(
                bias + r * 64 + ot * 16 + g * 4);
            #pragma unroll
            for (int nt = 0; nt < 4; ++nt) {
                const int n = n0 + nt * 16 + l15;
                if (n < NN) {
                    ushort4 pk;
                    pk.x = f2bf(acc[ot][nt][0] + bv.x);
                    pk.y = f2bf(acc[ot][nt][1] + bv.y);
                    pk.z = f2bf(acc[ot][nt][2] + bv.z);
                    pk.w = f2bf(acc[ot][nt][3] + bv.w);
                    *reinterpret_cast<ushort4*>(
                        out + ((size_t)n * NR + r) * 64 + ot * 16 + g * 4) = pk;
                }
            }
        }
    }
}

// ---------- CSR construction ----------
__global__ __launch_bounds__(256) void hist_kernel(const int* __restrict__ dst, int* __restrict__ cnt)
{
    const int e = blockIdx.x * 256 + threadIdx.x;
    if (e < NE) atomicAdd(&cnt[dst[e]], 1);
}

__global__ __launch_bounds__(256) void scan1_kernel(
    const int* __restrict__ cnt, int* __restrict__ offs, int* __restrict__ partial)
{
    __shared__ int s[256];
    const int t = threadIdx.x, i = blockIdx.x * 256 + t;
    const int v = (i < NN) ? cnt[i] : 0;
    s[t] = v;
    __syncthreads();
    #pragma unroll
    for (int off = 1; off < 256; off <<= 1) {
        const int x = (t >= off) ? s[t - off] : 0;
        __syncthreads();
        s[t] += x;
        __syncthreads();
    }
    if (i < NN) offs[i] = s[t] - v;
    if (t == 255) partial[blockIdx.x] = s[255];
}

__global__ __launch_bounds__(256) void scan2_kernel(int* __restrict__ partial, const int nblk)
{
    __shared__ int s[256];
    const int t = threadIdx.x;
    const int v = (t < nblk) ? partial[t] : 0;
    s[t] = v;
    __syncthreads();
    #pragma unroll
    for (int off = 1; off < 256; off <<= 1) {
        const int x = (t >= off) ? s[t - off] : 0;
        __syncthreads();
        s[t] += x;
        __syncthreads();
    }
    if (t < nblk) partial[t] = s[t] - v;
}

__global__ __launch_bounds__(256) void scan3_kernel(
    int* __restrict__ offs, const int* __restrict__ partial)
{
    const int i = blockIdx.x * 256 + threadIdx.x;
    if (i < NN) offs[i] += partial[blockIdx.x];
    if (i == 0) offs[NN] = NE;
}

// ---------- K2: fused logits + CSR fill. 8 lanes/edge, 16B table loads ----------
__global__ __launch_bounds__(256) void logits_fill_kernel(
    const unsigned short* __restrict__ pS, const unsigned short* __restrict__ pQ,
    const int* __restrict__ src, const int* __restrict__ dst,
    const int* __restrict__ rt, const int* __restrict__ nid,
    const float* __restrict__ attn, const int* __restrict__ offs,
    int* __restrict__ cursor,
    int* __restrict__ perm_src, float2* __restrict__ perm_e)
{
    __shared__ float al[512];       // attn: 8 * 2 * 32
    const int t = threadIdx.x;
    for (int i = t; i < 512; i += 256) al[i] = attn[i];
    __syncthreads();

    const int e = blockIdx.x * 32 + (t >> 3);
    if (e >= NE) return;
    const int sub = t & 7;          // 8 lanes/edge, 8 d each
    const int r = rt[e], s = src[e], q = nid[e];
    const int d0 = sub * 8;

    const u16x8 us = *reinterpret_cast<const u16x8*>(pS + ((size_t)s * NR + r) * 64 + d0);
    const u16x8 uq = *reinterpret_cast<const u16x8*>(pQ + ((size_t)q * NR + r) * 64 + d0);
    float p = 0.f;
    const float* a = &al[r * 64 + d0];
    #pragma unroll
    for (int i = 0; i < 8; ++i) {
        float v = bf2f((unsigned short)us[i]) + bf2f((unsigned short)uq[i]);
        v = v > 0.f ? v : 0.2f * v;
        p += v * a[i];
    }
    p += __shfl_xor(p, 1);
    p += __shfl_xor(p, 2);                 // subs 0-3: head0 sum; subs 4-7: head1 sum
    const float other = __shfl_xor(p, 4);  // sub0 gets head1
    if (sub == 0) {
        const int dn = dst[e];
        const int j = offs[dn] + atomicAdd(&cursor[dn], 1);
        perm_src[j] = s;
        perm_e[j] = make_float2(p, other);
    }
}

// ---------- K4: per-node softmax + aggregation (v3: 2 edges/iter, half-wave each) ----------
__global__ __launch_bounds__(256) void aggregate_kernel(
    const float* __restrict__ feat, const int* __restrict__ offs,
    const int* __restrict__ perm_src, const float2* __restrict__ perm_e,
    float* __restrict__ out)
{
    __shared__ float2 ebuf[4][64];
    __shared__ int    sbuf[4][64];
    const int wv = threadIdx.x >> 6;
    const int n = blockIdx.x * 4 + wv;
    if (n >= NN) return;
    const int lane = threadIdx.x & 63;
    const int h2 = lane >> 5;        // which edge of the pair
    const int dp = lane & 31;        // d-pair: covers d = 2dp, 2dp+1
    const int s0 = offs[n], s1 = offs[n + 1];
    float a00 = 0.f, a01 = 0.f, a10 = 0.f, a11 = 0.f;   // [head][even/odd d]
    float d0s = 0.f, d1s = 0.f;
    if (s1 > s0) {
        float m0 = -1e30f, m1 = -1e30f;
        for (int j = s0 + lane; j < s1; j += 64) {
            const float2 p = perm_e[j];
            m0 = fmaxf(m0, p.x); m1 = fmaxf(m1, p.y);
        }
        #pragma unroll
        for (int m = 32; m; m >>= 1) {
            m0 = fmaxf(m0, __shfl_xor(m0, m));
            m1 = fmaxf(m1, __shfl_xor(m1, m));
        }
        for (int c = s0; c < s1; c += 64) {
            const int cnt = min(64, s1 - c);
            if (lane < cnt) {
                const float2 p = perm_e[c + lane];
                const float e0 = __expf(p.x - m0);
                const float e1 = __expf(p.y - m1);
                d0s += e0; d1s += e1;
                ebuf[wv][lane] = make_float2(e0, e1);
                sbuf[wv][lane] = perm_src[c + lane];
            } else if (lane == cnt) {            // zero-weight pad for odd tails
                ebuf[wv][lane] = make_float2(0.f, 0.f);
                sbuf[wv][lane] = 0;
            }
            const int cp = cnt + (cnt & 1);
            #pragma unroll 4
            for (int k = 0; k < cp; k += 2) {
                const int ei = k + h2;
                const int sA = sbuf[wv][ei];
                const float2 w = ebuf[wv][ei];
                const float2 f = *reinterpret_cast<const float2*>(
                    &feat[(size_t)sA * 64 + dp * 2]);
                a00 += f.x * w.x; a01 += f.y * w.x;
                a10 += f.x * w.y; a11 += f.y * w.y;
            }
        }
        #pragma unroll
        for (int m = 32; m; m >>= 1) {
            d0s += __shfl_xor(d0s, m);
            d1s += __shfl_xor(d1s, m);
        }
        a00 += __shfl_xor(a00, 32); a01 += __shfl_xor(a01, 32);
        a10 += __shfl_xor(a10, 32); a11 += __shfl_xor(a11, 32);
        const float r0 = 1.f / d0s, r1 = 1.f / d1s;
        a00 *= r0; a01 *= r0; a10 *= r1; a11 *= r1;
    }
    if (h2 == 0)
        *reinterpret_cast<float2*>(&out[(size_t)n * 128 + dp * 2])      = make_float2(a00, a01);
    else
        *reinterpret_cast<float2*>(&out[(size_t)n * 128 + 64 + dp * 2]) = make_float2(a10, a11);
}

// ---------- minimal-workspace fallback: direct logits + atomic scatter ----------
__global__ __launch_bounds__(256) void logits_direct_kernel(
    const float* __restrict__ feat, const float* __restrict__ nq,
    const int* __restrict__ src, const int* __restrict__ dst,
    const int* __restrict__ rt, const int* __restrict__ nid,
    const float* __restrict__ fc_src, const float* __restrict__ fc_src_b,
    const float* __restrict__ fc_qual, const float* __restrict__ fc_qual_b,
    const float* __restrict__ attn,
    float* __restrict__ e_buf, unsigned* __restrict__ emax)
{
    __shared__ float Ws[64][64];
    __shared__ float Wq[64][64];
    __shared__ float bl[64];
    __shared__ float al[64];
    const int r = blockIdx.y;
    const int t = threadIdx.x;
    for (int i = t; i < 4096; i += 256) {
        ((float*)Ws)[i] = fc_src[(size_t)r * 4096 + i];
        ((float*)Wq)[i] = fc_qual[(size_t)r * 4096 + i];
    }
    if (t < 64) {
        bl[t] = fc_src_b[r * 64 + t] + fc_qual_b[r * 64 + t];
        al[t] = attn[r * 64 + t];
    }
    __syncthreads();

    const int lane = t & 63;
    const int wid = blockIdx.x * 4 + (t >> 6);
    const int nw = gridDim.x * 4;
    for (int e = wid; e < NE; e += nw) {
        if (rt[e] != r) continue;
        const int s = src[e], q = nid[e];
        float fv = feat[(size_t)s * 64 + lane];
        float qv = nq[(size_t)q * 64 + lane];
        float acc = bl[lane];
        for (int k = 0; k < 64; ++k) {
            acc += __shfl(fv, k) * Ws[k][lane];
            acc += __shfl(qv, k) * Wq[k][lane];
        }
        acc = acc > 0.f ? acc : 0.2f * acc;
        float p = acc * al[lane];
        #pragma unroll
        for (int m = 1; m < 32; m <<= 1) p += __shfl_xor(p, m);
        if ((lane & 31) == 0) {
            int h = lane >> 5;
            e_buf[(size_t)e * 2 + h] = p;
            atomicMax(&emax[(size_t)dst[e] * 2 + h], fkey(p));
        }
    }
}

__global__ __launch_bounds__(256) void expdenom_kernel(
    const int* __restrict__ dst, float* __restrict__ e_buf,
    const unsigned* __restrict__ emax, float* __restrict__ denom)
{
    const int i = blockIdx.x * 256 + threadIdx.x;
    if (i >= NE * 2) return;
    const int e = i >> 1, h = i & 1;
    const int dn = dst[e];
    const float m = funkey(emax[(size_t)dn * 2 + h]);
    const float ex = __expf(e_buf[i] - m);
    e_buf[i] = ex;
    unsafeAtomicAdd(&denom[(size_t)dn * 2 + h], ex);
}

__global__ __launch_bounds__(256) void scatter_kernel(
    const float* __restrict__ feat, const int* __restrict__ src, const int* __restrict__ dst,
    const float* __restrict__ ex, const float* __restrict__ denom, float* __restrict__ out)
{
    const int e = blockIdx.x * 4 + (threadIdx.x >> 6);
    if (e >= NE) return;
    const int lane = threadIdx.x & 63;
    const int s = src[e], dn = dst[e];
    const float f = feat[(size_t)s * 64 + lane];
    const float a0 = ex[(size_t)e * 2]     / denom[(size_t)dn * 2];
    const float a1 = ex[(size_t)e * 2 + 1] / denom[(size_t)dn * 2 + 1];
    unsafeAtomicAdd(&out[(size_t)dn * 128 + lane],      f * a0);
    unsafeAtomicAdd(&out[(size_t)dn * 128 + 64 + lane], f * a1);
}

extern "C" void kernel_launch(void* const* d_in, const int* in_sizes, int n_in,
                              void* d_out, int out_size, void* d_ws, size_t ws_size,
                              hipStream_t stream)
{
    const float* feat      = (const float*)d_in[0];
    const int*   src       = (const int*)d_in[1];
    const int*   dst       = (const int*)d_in[2];
    const int*   rt        = (const int*)d_in[3];
    const int*   nid       = (const int*)d_in[4];
    const float* fc_src    = (const float*)d_in[5];
    const float* fc_src_b  = (const float*)d_in[6];
    const float* nq        = (const float*)d_in[7];
    const float* fc_qual   = (const float*)d_in[8];
    const float* fc_qual_b = (const float*)d_in[9];
    const float* attn      = (const float*)d_in[10];
    float* out = (float*)d_out;

    char* ws = (char*)d_ws;

    // region0 (prep/proj inputs, all DEAD after proj):
    //   xS@0 (6,406,144)  xQ@6,406,144 (6,406,144)  WtS@12,812,288 (65,536)  WtQ@12,877,824 (65,536)
    // CSR block ALIASES region0 (written only after proj):
    //   cnt@0 (200,000)  cursor@262,144 (200,000)  offs@524,288 (200,016)
    //   partial@786,432 (1,024)  perm_src@1,048,576 (3,200,000)  perm_e@4,248,576 (6,400,000)
    // tables: pS@13,000,000 (51.2MB)  pQ@64,200,000 (51.2MB)  -> need 115.4MB (proven available)
    const size_t XBYTES = (size_t)NN_PAD * 64 * 2;               // 6,406,144
    unsigned short* xS  = (unsigned short*)ws;
    unsigned short* xQ  = (unsigned short*)(ws + XBYTES);
    unsigned short* WtS = (unsigned short*)(ws + 2 * XBYTES);
    unsigned short* WtQ = (unsigned short*)(ws + 2 * XBYTES + 65536);
    const size_t PS_OFF = 13000000;
    const size_t TBYTES = (size_t)NN * NR * 64 * 2;              // 51,200,000
    const size_t need2  = PS_OFF + 2 * TBYTES;                   // 115.4 MB

    if (ws_size >= need2) {
        unsigned short* pS = (unsigned short*)(ws + PS_OFF);
        unsigned short* pQ = pS + (size_t)NN * NR * 64;
        int*    cnt      = (int*)ws;
        int*    cursor   = (int*)(ws + 262144);
        int*    offs     = (int*)(ws + 524288);
        int*    partial  = (int*)(ws + 786432);
        int*    perm_src = (int*)(ws + 1048576);
        float2* perm_e   = (float2*)(ws + 4248576);

        prep_kernel<<<(2 * (NN * 64 / 4) + 65536 + 255) / 256, 256, 0, stream>>>(
            feat, nq, fc_src, fc_qual, xS, xQ, WtS, WtQ);
        const int nchunk = (NN + 63) / 64;                       // 782
        dim3 gp((nchunk + 3) / 4, 2);
        proj_mfma_kernel<<<gp, 256, 0, stream>>>(
            xS, xQ, WtS, WtQ, fc_src_b, fc_qual_b, pS, pQ);

        hipMemsetAsync(ws, 0, 524288, stream);                   // cnt + cursor
        hist_kernel<<<(NE + 255) / 256, 256, 0, stream>>>(dst, cnt);
        const int nblk = (NN + 255) / 256;
        scan1_kernel<<<nblk, 256, 0, stream>>>(cnt, offs, partial);
        scan2_kernel<<<1, 256, 0, stream>>>(partial, nblk);
        scan3_kernel<<<nblk, 256, 0, stream>>>(offs, partial);

        logits_fill_kernel<<<(NE + 31) / 32, 256, 0, stream>>>(
            pS, pQ, src, dst, rt, nid, attn, offs, cursor, perm_src, perm_e);
        aggregate_kernel<<<(NN + 3) / 4, 256, 0, stream>>>(
            feat, offs, perm_src, perm_e, out);
    } else {
        // minimal-workspace fallback (atomic path)
        float*    e_buf = (float*)ws;
        unsigned* emax  = (unsigned*)(ws + (size_t)NE * 2 * 4);
        float*    denom = (float*)(ws + (size_t)NE * 2 * 4 + (size_t)NN * 2 * 4);
        hipMemsetAsync(out, 0, (size_t)out_size * sizeof(float), stream);
        hipMemsetAsync(emax, 0, (size_t)NN * 2 * 4 * 2, stream);
        dim3 g(256, NR);
        logits_direct_kernel<<<g, 256, 0, stream>>>(
            feat, nq, src, dst, rt, nid, fc_src, fc_src_b, fc_qual, fc_qual_b,
            attn, e_buf, emax);
        expdenom_kernel<<<(NE * 2 + 255) / 256, 256, 0, stream>>>(dst, e_buf, emax, denom);
        scatter_kernel<<<(NE + 3) / 4, 256, 0, stream>>>(feat, src, dst, e_buf, denom, out);
    }
}